// Round 13
// baseline (690.780 us; speedup 1.0000x reference)
//
#include <hip/hip_runtime.h>
#include <hip/hip_bf16.h>
#include <cstdio>

// ---------------------------------------------------------------------------
// SyndromeTransformerLayer on MI355X.  Round 13: m-looped counted GEMMs.
// k_gemm / k_ff1: each block processes MT m-tiles sequentially -> U=MT*NT
// deep loop (16-32 steps), enabling the conv-proven counted-vmcnt pipeline
// (depth-2, vmcnt(8/6), raw barriers, C-write at m-tile boundaries).
// All GEMM grids sized for full co-residency (no block-wave tail).
// conv (R9 counted, 155us/37% MfmaUtil), attn (R9), LN kernels unchanged.
// Workspace: 137,527,296 B, phase-overlapped slots.
// ---------------------------------------------------------------------------

typedef __attribute__((ext_vector_type(8))) short s8v;    // 8 bf16 (4 VGPRs)
typedef __attribute__((ext_vector_type(4))) float f32x4;  // MFMA accumulator
typedef unsigned short u16;

constexpr int kB = 64, kS = 575, kD = 256, kH = 8, kP = 576, kFF = 1024;
constexpr int kRows = kB * kS;  // 36800
constexpr float kEps = 1e-5f;
constexpr float kScale = 0.17677669529663687f;  // 1/sqrt(32)
constexpr size_t kPdStride = 9420800;  // u16 elements per conv partial

__device__ __forceinline__ u16 f2b(float f) {
  __hip_bfloat16 h = __float2bfloat16(f);
  return *reinterpret_cast<u16*>(&h);
}
__device__ __forceinline__ void unpack2(unsigned int w, float& lo, float& hi) {
  union { float f; unsigned int u; } a, b;
  a.u = w << 16;
  b.u = w & 0xffff0000u;
  lo = a.f;
  hi = b.f;
}

__device__ __forceinline__ void gll16(const void* g, void* l) {
  __builtin_amdgcn_global_load_lds((const __attribute__((address_space(1))) void*)g,
                                   (__attribute__((address_space(3))) void*)l, 16, 0, 0);
}

// ------------------------------ packing ------------------------------------
// One block per (i,co) pair: reads 2304 contiguous floats (thread ci takes its
// 9), writes wc[tap][co][ci].
__global__ void k_pack_convw(const float* __restrict__ cw, u16* __restrict__ wc) {
  const int blk = blockIdx.x;   // i*256 + co
  const int ci = threadIdx.x;
  const int i = blk >> 8, co = blk & 255;
  const float* src = cw + (size_t)blk * 2304 + ci * 9;
  float v[9];
#pragma unroll
  for (int r = 0; r < 9; ++r) v[r] = src[r];
#pragma unroll
  for (int r = 0; r < 9; ++r)
    wc[(((size_t)(i * 9 + r)) << 16) + (co << 8) + ci] = f2b(v[r]);
}

__global__ void k_tobf16(const float* __restrict__ in, u16* __restrict__ out, int n) {
  int i = blockIdx.x * 256 + threadIdx.x;
  if (i < n) out[i] = f2b(in[i]);
}

// X0[b][p][c]: p=0 is the zero pad row, else state[b][p-1][c], bf16.
// Extra block (bp == kB*kP) writes the 256-element zero row used by k_conv.
__global__ void k_make_x0(const float* __restrict__ state, u16* __restrict__ x0,
                          u16* __restrict__ zrow) {
  int bp = blockIdx.x;  // b*576 + p, or kB*kP for the zero row
  int c = threadIdx.x;
  if (bp == kB * kP) { zrow[c] = 0; return; }
  int p = bp % kP;
  int b = bp / kP;
  float v = (p == 0) ? 0.f : state[((size_t)(b * kS + p - 1)) * kD + c];
  x0[(size_t)bp * kD + c] = f2b(v);
}

// ------------------------------ GEMM (m-looped counted pipeline) -----------
// C[M][N] = A[M][K](bf16) @ Bw[N][K]^T(bf16) + bias[N], bf16 out.
// Each block: MT m-tiles of 128 rows, NT=(K/64) K-steps each -> U=MT*NT deep
// counted-vmcnt pipeline (vmcnt(8), raw barriers, stage(u+2) after barrier2,
// C-write + acc reset at each m-tile boundary).  Chunk-XOR LDS swizzle.
// grid = (288/MT, N/128).  K = NT*64, NT = 1<<ntSh.
__global__ __launch_bounds__(256) void k_gemm(const u16* __restrict__ A,
                                              const u16* __restrict__ Bw,
                                              const float* __restrict__ bias,
                                              u16* __restrict__ Cb,
                                              int M, int N, int K, int MT, int ntSh) {
  __shared__ u16 As[2][8192];  // [128][64] x2
  __shared__ u16 Bs[2][8192];
  const int t = threadIdx.x;
  const int wave = t >> 6, lane = t & 63;
  const int wm = wave >> 1, wn = wave & 1;
  const int lr = lane & 15, lk = lane >> 4;
  const int n0 = blockIdx.y * 128;
  const int lrow = lane >> 3;                // 0..7
  const int swzk = ((lane & 7) ^ lrow) * 8;  // swizzled source chunk (u16)
  int roff[4];
  const u16* gb[4];
#pragma unroll
  for (int i = 0; i < 4; ++i) {
    int r = 8 * wave + lrow + 32 * i;
    roff[i] = r;
    gb[i] = Bw + (size_t)(n0 + r) * K + swzk;
  }
  const int NT = 1 << ntSh;
  const int U = MT << ntSh;
  auto stage = [&](int u, int buf) {
    const int mt = u >> ntSh;
    const int kt = (u & (NT - 1)) << 6;
    const int m0 = (blockIdx.x * MT + mt) << 7;
#pragma unroll
    for (int i = 0; i < 4; ++i) {
      int ra = m0 + roff[i];
      if (ra > M - 1) ra = M - 1;  // clamp: garbage rows are never stored
      gll16(A + (size_t)ra * K + kt + swzk, &As[buf][i * 2048 + wave * 512]);
      gll16(gb[i] + kt, &Bs[buf][i * 2048 + wave * 512]);
    }
  };
  f32x4 acc[4][4] = {};
  stage(0, 0);
  if (U > 1) stage(1, 1);
  for (int u = 0; u < U; ++u) {
    const int cur = u & 1;
    if (u + 1 < U)
      asm volatile("s_waitcnt vmcnt(8)" ::: "memory");
    else
      asm volatile("s_waitcnt vmcnt(0)" ::: "memory");
    __builtin_amdgcn_s_barrier();
    s8v af[2][4], bfr[2][4];
#pragma unroll
    for (int kk = 0; kk < 2; ++kk)
#pragma unroll
      for (int i = 0; i < 4; ++i) {
        const int rA = wm * 64 + i * 16 + lr;
        const int rB = wn * 64 + i * 16 + lr;
        af[kk][i] = *(const s8v*)(&As[cur][rA * 64 + ((kk * 32 + lk * 8) ^ ((rA & 7) << 3))]);
        bfr[kk][i] = *(const s8v*)(&Bs[cur][rB * 64 + ((kk * 32 + lk * 8) ^ ((rB & 7) << 3))]);
      }
#pragma unroll
    for (int kk = 0; kk < 2; ++kk)
#pragma unroll
      for (int i = 0; i < 4; ++i)
#pragma unroll
        for (int j = 0; j < 4; ++j)
          acc[i][j] = __builtin_amdgcn_mfma_f32_16x16x32_bf16(af[kk][i], bfr[kk][j], acc[i][j], 0, 0, 0);
    __builtin_amdgcn_s_barrier();  // all waves done reading buf
    if (u + 2 < U) stage(u + 2, cur);
    if ((u & (NT - 1)) == NT - 1) {
      // end of this m-tile: write C, reset accumulator
      const int m0 = (blockIdx.x * MT + (u >> ntSh)) << 7;
#pragma unroll
      for (int i = 0; i < 4; ++i) {
        const int rbase = m0 + wm * 64 + i * 16 + lk * 4;
#pragma unroll
        for (int j = 0; j < 4; ++j) {
          const int col = n0 + wn * 64 + j * 16 + lr;
          const float bv = bias[col];
#pragma unroll
          for (int q = 0; q < 4; ++q) {
            int r = rbase + q;
            if (r < M) Cb[(size_t)r * N + col] = f2b(acc[i][j][q] + bv);
          }
          acc[i][j] = (f32x4){0.f, 0.f, 0.f, 0.f};
        }
      }
    }
  }
}

// ------------------------------ FF1 + fused sigmoid gate (m-looped) --------
// H[r][c] = (A@Wff[c]^T + pb[c]) * sigmoid(A@Wff[1024+c]^T + gb[c]).
// BK=32, MT m-tiles/block -> U=MT*8 deep counted pipeline (vmcnt(6)).
// Chunk-XOR swizzle (4 chunks/row).  grid = (288/MT, 8).
__global__ __launch_bounds__(256) void k_ff1(const u16* __restrict__ A,
                                             const u16* __restrict__ Wf,
                                             const float* __restrict__ pb,
                                             const float* __restrict__ gb,
                                             u16* __restrict__ H, int M, int MT) {
  __shared__ u16 As[2][4096];
  __shared__ u16 Bp[2][4096];
  __shared__ u16 Bg[2][4096];
  const int t = threadIdx.x;
  const int wave = t >> 6;
  const int wm = wave >> 1, wn = wave & 1;
  const int lr = t & 15, lk = (t & 63) >> 4;
  const int n0 = blockIdx.y * 128;
  const int koff = (((t & 3) ^ ((t >> 2) & 3)) * 8);  // swizzled source chunk
  const int r0 = t >> 2;
  const u16* gP0 = Wf + (size_t)(n0 + r0) * kD + koff;
  const u16* gP1 = gP0 + (size_t)64 * kD;
  const u16* gG0 = gP0 + (size_t)1024 * kD;
  const u16* gG1 = gP1 + (size_t)1024 * kD;
  const int U = MT << 3;
  auto stage = [&](int u, int buf) {
    const int mt = u >> 3;
    const int kt = (u & 7) << 5;
    const int m0 = (blockIdx.x * MT + mt) << 7;
    int ra = m0 + r0;
    int rb = ra + 64;
    if (ra > M - 1) ra = M - 1;
    if (rb > M - 1) rb = M - 1;
    gll16(A + (size_t)ra * kD + kt + koff, &As[buf][wave * 512]);
    gll16(A + (size_t)rb * kD + kt + koff, &As[buf][2048 + wave * 512]);
    gll16(gP0 + kt, &Bp[buf][wave * 512]);
    gll16(gP1 + kt, &Bp[buf][2048 + wave * 512]);
    gll16(gG0 + kt, &Bg[buf][wave * 512]);
    gll16(gG1 + kt, &Bg[buf][2048 + wave * 512]);
  };
  f32x4 ap[4][4] = {};
  f32x4 ag[4][4] = {};
  stage(0, 0);
  if (U > 1) stage(1, 1);
  for (int u = 0; u < U; ++u) {
    const int cur = u & 1;
    if (u + 1 < U)
      asm volatile("s_waitcnt vmcnt(6)" ::: "memory");
    else
      asm volatile("s_waitcnt vmcnt(0)" ::: "memory");
    __builtin_amdgcn_s_barrier();
    s8v af[4], bp4[4], bg4[4];
#pragma unroll
    for (int i = 0; i < 4; ++i) {
      const int rA = wm * 64 + i * 16 + lr;
      const int rB = wn * 64 + i * 16 + lr;
      const int oA = rA * 32 + ((lk * 8) ^ ((rA & 3) << 3));
      const int oB = rB * 32 + ((lk * 8) ^ ((rB & 3) << 3));
      af[i] = *(const s8v*)(&As[cur][oA]);
      bp4[i] = *(const s8v*)(&Bp[cur][oB]);
      bg4[i] = *(const s8v*)(&Bg[cur][oB]);
    }
#pragma unroll
    for (int i = 0; i < 4; ++i)
#pragma unroll
      for (int j = 0; j < 4; ++j) {
        ap[i][j] = __builtin_amdgcn_mfma_f32_16x16x32_bf16(af[i], bp4[j], ap[i][j], 0, 0, 0);
        ag[i][j] = __builtin_amdgcn_mfma_f32_16x16x32_bf16(af[i], bg4[j], ag[i][j], 0, 0, 0);
      }
    __builtin_amdgcn_s_barrier();
    if (u + 2 < U) stage(u + 2, cur);
    if ((u & 7) == 7) {
      const int m0 = (blockIdx.x * MT + (u >> 3)) << 7;
#pragma unroll
      for (int i = 0; i < 4; ++i) {
        const int rbase = m0 + wm * 64 + i * 16 + lk * 4;
#pragma unroll
        for (int j = 0; j < 4; ++j) {
          const int col = n0 + wn * 64 + j * 16 + lr;
          const float pbv = pb[col], gbv = gb[col];
#pragma unroll
          for (int q = 0; q < 4; ++q) {
            int r = rbase + q;
            if (r < M) {
              float p = ap[i][j][q] + pbv;
              float g = ag[i][j][q] + gbv;
              H[(size_t)r * kFF + col] = f2b(p * (1.f / (1.f + __expf(-g))));
            }
          }
          ap[i][j] = (f32x4){0.f, 0.f, 0.f, 0.f};
          ag[i][j] = (f32x4){0.f, 0.f, 0.f, 0.f};
        }
      }
    }
  }
}

// ------------------------------ conv (counted-vmcnt pipeline, R9) ----------
__global__ __launch_bounds__(256) void k_conv(const u16* __restrict__ X0,
                                              const u16* __restrict__ zrow,
                                              const u16* __restrict__ Wc,
                                              const float* __restrict__ cb,
                                              u16* __restrict__ pd) {
  __shared__ u16 As[2][8192];  // [128][64] x2
  __shared__ u16 Bs[2][8192];
  const int t = threadIdx.x;
  const int wave = t >> 6, lane = t & 63;
  const int wm = wave >> 1, wn = wave & 1;
  const int lr = lane & 15, lk = lane >> 4;
  const int m0 = blockIdx.x * 128;
  const int n0 = blockIdx.y * 128;
  const int di = blockIdx.z;
  const int dil = 1 << di;
  const int lrow = lane >> 3;
  const int swzk = ((lane & 7) ^ lrow) * 8;
  const u16* Wd = Wc + ((size_t)di * 9 << 16);
  int py[4], px[4];
  const u16* xrow[4];
  const u16* gw[4];
#pragma unroll
  for (int i = 0; i < 4; ++i) {
    int r = 8 * wave + lrow + 32 * i;
    int m = m0 + r;                 // 0..36863
    int bbv = m / 576;
    int p = m - bbv * 576;
    py[i] = p / 24;
    px[i] = p - py[i] * 24;
    xrow[i] = X0 + (((size_t)(bbv * kP)) << 8) + swzk;
    gw[i] = Wd + (size_t)(n0 + r) * kD + swzk;
  }
  const u16* S0[4];
  const u16* S1[4];
  auto csrc = [&](const u16** dst, int dyv, int dxv) {
#pragma unroll
    for (int i = 0; i < 4; ++i) {
      const int ny = py[i] + dyv, nx = px[i] + dxv;
      const bool v = ((unsigned)ny < 24u) & ((unsigned)nx < 24u);
      dst[i] = v ? xrow[i] + ((ny * 24 + nx) << 8) : zrow + swzk;
    }
  };
  auto stage = [&](const u16* const* S, size_t woff, int kc, int buf) {
#pragma unroll
    for (int i = 0; i < 4; ++i) {
      gll16(S[i] + kc, &As[buf][i * 2048 + wave * 512]);
      gll16(gw[i] + woff + kc, &Bs[buf][i * 2048 + wave * 512]);
    }
  };
  f32x4 acc[4][4] = {};
  csrc(S0, -dil, -dil);   // tap 0
  stage(S0, 0, 0, 0);     // step 0 -> buf 0
  stage(S0, 0, 64, 1);    // step 1 -> buf 1
  for (int tap = 0; tap < 9; ++tap) {
    if (tap < 8) {
      const int tn = tap + 1;
      csrc(S1, (tn / 3 - 1) * dil, (tn % 3 - 1) * dil);
    }
    const size_t woff = (size_t)tap << 16;
#pragma unroll
    for (int c = 0; c < 4; ++c) {
      const int buf = c & 1;  // step s = tap*4+c; s&1 == c&1
      if (c == 3 && tap == 8) {
        asm volatile("s_waitcnt vmcnt(0)" ::: "memory");
      } else {
        asm volatile("s_waitcnt vmcnt(8)" ::: "memory");
      }
      __builtin_amdgcn_s_barrier();
      s8v af[2][4], bfr[2][4];
#pragma unroll
      for (int kk = 0; kk < 2; ++kk)
#pragma unroll
        for (int ii = 0; ii < 4; ++ii) {
          const int rA = wm * 64 + ii * 16 + lr;
          const int rB = wn * 64 + ii * 16 + lr;
          af[kk][ii] = *(const s8v*)(&As[buf][rA * 64 + ((kk * 32 + lk * 8) ^ ((rA & 7) << 3))]);
          bfr[kk][ii] = *(const s8v*)(&Bs[buf][rB * 64 + ((kk * 32 + lk * 8) ^ ((rB & 7) << 3))]);
        }
#pragma unroll
      for (int kk = 0; kk < 2; ++kk)
#pragma unroll
        for (int ii = 0; ii < 4; ++ii)
#pragma unroll
          for (int jj = 0; jj < 4; ++jj)
            acc[ii][jj] = __builtin_amdgcn_mfma_f32_16x16x32_bf16(af[kk][ii], bfr[kk][jj], acc[ii][jj], 0, 0, 0);
      __builtin_amdgcn_s_barrier();
      if (c == 0) {
        stage(S0, woff, 128, buf);
      } else if (c == 1) {
        stage(S0, woff, 192, buf);
      } else if (c == 2) {
        if (tap < 8) stage(S1, woff + 65536, 0, buf);
      } else {
        if (tap < 8) stage(S1, woff + 65536, 64, buf);
      }
    }
#pragma unroll
    for (int i = 0; i < 4; ++i) S0[i] = S1[i];
  }
  u16* pdo = pd + (size_t)di * kPdStride;
#pragma unroll
  for (int i2 = 0; i2 < 4; ++i2) {
    const int mbase = m0 + wm * 64 + i2 * 16 + lk * 4;
#pragma unroll
    for (int j = 0; j < 4; ++j) {
      const int col = n0 + wn * 64 + j * 16 + lr;
      const float bv = cb[di * kD + col];
#pragma unroll
      for (int q = 0; q < 4; ++q) {
        const int m = mbase + q;
        const int b2 = m / 576;
        const int p = m - b2 * 576;
        if (p >= 1)
          pdo[((size_t)(b2 * kS + p - 1) << 8) + col] = f2b(acc[i2][j][q] + bv);
      }
    }
  }
}

// ------------------------------ attention (MFMA flash, R9 version) ---------
// Reference reshape quirk: q.reshape(b,h,s,hd) on (b,s,256) means head h, pos s'
// = contiguous 32 elems at flat offset h*575*32 + s'*32 of the q block.
// Block: 4 waves, 64 q-rows; K-loop over 575 keys in 9 tiles of 64 (masked).
__global__ __launch_bounds__(256) void k_attn2(const u16* __restrict__ qkv,
                                               const float* __restrict__ bias,
                                               u16* __restrict__ outp) {
  __shared__ u16 KsS[2][2048];  // [64 keys][32 d], swizzled
  __shared__ u16 VtS[2][2048];  // [32 d][64 keys], swizzled
  __shared__ u16 PsS[4][1024];  // per-wave [16 q][64 keys], swizzled
  const int qt = blockIdx.x, h = blockIdx.y, b = blockIdx.z;
  const int tid = threadIdx.x;
  const int w = tid >> 6, lane = tid & 63;
  const int lg = lane >> 4, lr = lane & 15;
  const int q0 = qt * 64;
  const int qrow_a = q0 + w * 16 + lr;
  const int qrow_ac = qrow_a < kS ? qrow_a : kS - 1;
  s8v qf;
  {
    int F = h * (kS * 32) + qrow_ac * 32 + lg * 8;
    qf = *(const s8v*)(qkv + ((size_t)(b * kS + (F >> 8))) * 768 + (F & 255));
  }
  const int trel = tid >> 2;
  const int dcol = (tid & 3) * 8;
  float mrun[4], lsum[4];
#pragma unroll
  for (int r = 0; r < 4; ++r) { mrun[r] = -1e30f; lsum[r] = 0.f; }
  f32x4 o0 = {0.f, 0.f, 0.f, 0.f}, o1 = {0.f, 0.f, 0.f, 0.f};
  const f32x4 zf = {0.f, 0.f, 0.f, 0.f};
  const int qrow_s = q0 + w * 16 + lg * 4;  // +r
  const size_t kvrowbase = (size_t)(b * kS) * 768;

  for (int kt = 0; kt < 9; ++kt) {
    const int t0 = kt * 64;
    const int buf = kt & 1;
    {
      const int tg = t0 + trel;
      const bool tv = tg < kS;
      const int tcl = tv ? tg : kS - 1;
      const int Fk = h * (kS * 32) + tcl * 32 + dcol;
      const u16* kp = qkv + kvrowbase + (size_t)(Fk >> 8) * 768 + 256 + (Fk & 255);
      uint4 kd = {0, 0, 0, 0}, vd = {0, 0, 0, 0};
      if (tv) {
        kd = *(const uint4*)kp;
        vd = *(const uint4*)(kp + 256);
      }
      *(uint4*)&KsS[buf][trel * 32 + (dcol ^ ((trel & 3) << 3))] = kd;
      union { uint4 u4; u16 us[8]; } vu;
      vu.u4 = vd;
#pragma unroll
      for (int j = 0; j < 8; ++j) {
        const int d = dcol + j;
        VtS[buf][d * 64 + (trel ^ ((d & 7) << 3))] = vu.us[j];
      }
    }
    float bv[4][4];  // [j key-subtile][r q-row]
#pragma unroll
    for (int r = 0; r < 4; ++r) {
      const int qr = qrow_s + r;
      const float* bp = bias + ((size_t)h * kS + (qr < kS ? qr : kS - 1)) * kS;
#pragma unroll
      for (int j = 0; j < 4; ++j) {
        const int tg = t0 + j * 16 + lr;
        bv[j][r] = (tg < kS) ? bp[tg] : -1e30f;
      }
    }
    __syncthreads();
    f32x4 sc[4];
#pragma unroll
    for (int j = 0; j < 4; ++j) {
      const int krow = j * 16 + lr;
      s8v kf = *(const s8v*)&KsS[buf][krow * 32 + ((lg * 8) ^ ((krow & 3) << 3))];
      sc[j] = __builtin_amdgcn_mfma_f32_16x16x32_bf16(qf, kf, zf, 0, 0, 0);
    }
#pragma unroll
    for (int r = 0; r < 4; ++r) {
      float s4[4];
      float sm = -1e30f;
#pragma unroll
      for (int j = 0; j < 4; ++j) {
        s4[j] = fmaf(sc[j][r], kScale, bv[j][r]);
        sm = fmaxf(sm, s4[j]);
      }
      sm = fmaxf(sm, __shfl_xor(sm, 1));
      sm = fmaxf(sm, __shfl_xor(sm, 2));
      sm = fmaxf(sm, __shfl_xor(sm, 4));
      sm = fmaxf(sm, __shfl_xor(sm, 8));
      const float nm = fmaxf(mrun[r], sm);
      const float corr = __expf(mrun[r] - nm);
      mrun[r] = nm;
      float psum = 0.f;
      const int prow = lg * 4 + r;
#pragma unroll
      for (int j = 0; j < 4; ++j) {
        const float p = __expf(s4[j] - nm);
        psum += p;
        PsS[w][prow * 64 + ((j * 16 + lr) ^ ((prow & 7) << 3))] = f2b(p);
      }
      lsum[r] = fmaf(lsum[r], corr, psum);
      o0[r] *= corr;
      o1[r] *= corr;
    }
#pragma unroll
    for (int c = 0; c < 2; ++c) {
      const int pcol = c * 32 + lg * 8;
      s8v pf = *(const s8v*)&PsS[w][lr * 64 + (pcol ^ ((lr & 7) << 3))];
      s8v vf0 = *(const s8v*)&VtS[buf][lr * 64 + (pcol ^ ((lr & 7) << 3))];
      s8v vf1 = *(const s8v*)&VtS[buf][(16 + lr) * 64 + (pcol ^ (((16 + lr) & 7) << 3))];
      o0 = __builtin_amdgcn_mfma_f32_16x16x32_bf16(pf, vf0, o0, 0, 0, 0);
      o1 = __builtin_amdgcn_mfma_f32_16x16x32_bf16(pf, vf1, o1, 0, 0, 0);
    }
  }
#pragma unroll
  for (int r = 0; r < 4; ++r) {
    float lt = lsum[r];
    lt += __shfl_xor(lt, 1);
    lt += __shfl_xor(lt, 2);
    lt += __shfl_xor(lt, 4);
    lt += __shfl_xor(lt, 8);
    const float inv = 1.f / lt;
    const int qr = qrow_s + r;
    if (qr < kS) {
      u16* op = outp + ((size_t)(b * kS + qr)) * kD + h * 32;
      op[lr] = f2b(o0[r] * inv);
      op[16 + lr] = f2b(o1[r] * inv);
    }
  }
}

// ------------------------------ add + LayerNorm ----------------------------
__global__ __launch_bounds__(256) void k_add_ln(const float* __restrict__ xa,
                                                const u16* __restrict__ xb,
                                                const float* __restrict__ g,
                                                const float* __restrict__ be,
                                                float* __restrict__ of, u16* __restrict__ ob) {
  const int wave = threadIdx.x >> 6, lane = threadIdx.x & 63;
  const int row = blockIdx.x * 4 + wave;
  const float4 a = ((const float4*)(xa + (size_t)row * kD))[lane];
  uint2 bw = ((const uint2*)(xb + (size_t)row * kD))[lane];
  float b0, b1, b2, b3;
  unpack2(bw.x, b0, b1);
  unpack2(bw.y, b2, b3);
  float x0 = a.x + b0, x1 = a.y + b1, x2 = a.z + b2, x3 = a.w + b3;
  float sum = x0 + x1 + x2 + x3;
  float sq = fmaf(x0, x0, fmaf(x1, x1, fmaf(x2, x2, x3 * x3)));
  for (int off = 1; off < 64; off <<= 1) {
    sum += __shfl_xor(sum, off);
    sq += __shfl_xor(sq, off);
  }
  const float mean = sum * (1.f / 256.f);
  const float var = sq * (1.f / 256.f) - mean * mean;
  const float rs = rsqrtf(var + kEps);
  const float4 gg = ((const float4*)g)[lane];
  const float4 bt = ((const float4*)be)[lane];
  float y0 = (x0 - mean) * rs * gg.x + bt.x;
  float y1 = (x1 - mean) * rs * gg.y + bt.y;
  float y2 = (x2 - mean) * rs * gg.z + bt.z;
  float y3 = (x3 - mean) * rs * gg.w + bt.w;
  float4 yo = {y0, y1, y2, y3};
  ((float4*)(of + (size_t)row * kD))[lane] = yo;
  if (ob) {
    u16* po = ob + (size_t)row * kD + lane * 4;
    po[0] = f2b(y0); po[1] = f2b(y1); po[2] = f2b(y2); po[3] = f2b(y3);
  }
}

// add+LN over state + three bf16 conv partials (LN1).
__global__ __launch_bounds__(256) void k_add_ln3(const float* __restrict__ xa,
                                                 const u16* __restrict__ pa,
                                                 const u16* __restrict__ pbq,
                                                 const u16* __restrict__ pc,
                                                 const float* __restrict__ g,
                                                 const float* __restrict__ be,
                                                 float* __restrict__ of, u16* __restrict__ ob) {
  const int wave = threadIdx.x >> 6, lane = threadIdx.x & 63;
  const int row = blockIdx.x * 4 + wave;
  const size_t base = (size_t)row * kD;
  const float4 a = ((const float4*)(xa + base))[lane];
  uint2 w0 = ((const uint2*)(pa + base))[lane];
  uint2 w1 = ((const uint2*)(pbq + base))[lane];
  uint2 w2 = ((const uint2*)(pc + base))[lane];
  float a0, a1, a2, a3, c0, c1, c2, c3, d0, d1, d2, d3;
  unpack2(w0.x, a0, a1); unpack2(w0.y, a2, a3);
  unpack2(w1.x, c0, c1); unpack2(w1.y, c2, c3);
  unpack2(w2.x, d0, d1); unpack2(w2.y, d2, d3);
  float x0 = a.x + a0 + c0 + d0, x1 = a.y + a1 + c1 + d1;
  float x2 = a.z + a2 + c2 + d2, x3 = a.w + a3 + c3 + d3;
  float sum = x0 + x1 + x2 + x3;
  float sq = fmaf(x0, x0, fmaf(x1, x1, fmaf(x2, x2, x3 * x3)));
  for (int off = 1; off < 64; off <<= 1) {
    sum += __shfl_xor(sum, off);
    sq += __shfl_xor(sq, off);
  }
  const float mean = sum * (1.f / 256.f);
  const float var = sq * (1.f / 256.f) - mean * mean;
  const float rs = rsqrtf(var + kEps);
  const float4 gg = ((const float4*)g)[lane];
  const float4 bt = ((const float4*)be)[lane];
  float y0 = (x0 - mean) * rs * gg.x + bt.x;
  float y1 = (x1 - mean) * rs * gg.y + bt.y;
  float y2 = (x2 - mean) * rs * gg.z + bt.z;
  float y3 = (x3 - mean) * rs * gg.w + bt.w;
  float4 yo = {y0, y1, y2, y3};
  ((float4*)(of + base))[lane] = yo;
  u16* po = ob + base + lane * 4;
  po[0] = f2b(y0); po[1] = f2b(y1); po[2] = f2b(y2); po[3] = f2b(y3);
}

// ------------------------------ launch -------------------------------------
extern "C" void kernel_launch(void* const* d_in, const int* in_sizes, int n_in,
                              void* d_out, int out_size, void* d_ws, size_t ws_size,
                              hipStream_t stream) {
  const float* state = (const float*)d_in[0];
  const float* conv_w = (const float*)d_in[1];
  const float* conv_b = (const float*)d_in[2];
  const float* qkv_w = (const float*)d_in[3];
  const float* qkv_b = (const float*)d_in[4];
  const float* o_w = (const float*)d_in[5];
  const float* o_b = (const float*)d_in[6];
  const float* attn_bias = (const float*)d_in[7];
  const float* ffp_w = (const float*)d_in[8];
  const float* ffp_b = (const float*)d_in[9];
  const float* ffg_w = (const float*)d_in[10];
  const float* ffg_b = (const float*)d_in[11];
  const float* ffo_w = (const float*)d_in[12];
  const float* ffo_b = (const float*)d_in[13];
  const float* n1_g = (const float*)d_in[14];
  const float* n1_b = (const float*)d_in[15];
  const float* n2_g = (const float*)d_in[16];
  const float* n2_b = (const float*)d_in[17];
  const float* n3_g = (const float*)d_in[18];
  const float* n3_b = (const float*)d_in[19];

  // ---- workspace layout: 137,527,296 bytes, phase-overlapped ----
  constexpr size_t kWsNeed = 137527296;
  if (ws_size < kWsNeed) {
    fprintf(stderr, "[kernel] ws_size=%zu < need=%zu\n", ws_size, kWsNeed);
    return;
  }
  char* ws = (char*)d_ws;
  u16* Wc = (u16*)(ws + 0);             // [27][256][256] bf16  (3,538,944 B)
  u16* Wqkv = (u16*)(ws + 3538944);     // [768][256]
  u16* Wo = (u16*)(ws + 3932160);       // [256][256]
  u16* Wff = (u16*)(ws + 4063232);      // [2048][256] (proj;gate)
  u16* Wffo = (u16*)(ws + 5111808);     // [256][1024]  (ends 5,636,096)
  float* stF = (float*)(ws + 5636096);  // [36800][256] f32 state (37,683,200 B)
  u16* stB = (u16*)(ws + 43319296);     // [36800][256] bf16 (18,841,600 B)
  char* S4 = ws + 62160896;             // 75,366,400 B shared slot
  // conv phase overlays:
  u16* X0 = (u16*)(ws + 5636096);       // in stF slot: [64][576][256] bf16
  u16* zrow = (u16*)(ws + 43319296);    // in stB slot: 256 zeros
  u16* pd = (u16*)S4;                   // 3 partials, stride kPdStride u16
  // attn/ffn phase overlays:
  u16* qkvb = (u16*)S4;                 // [36800][768] bf16 (56.5 MB)
  u16* attnout = (u16*)(S4 + 56524800); // [36800][256] bf16
  u16* oprojb = (u16*)S4;               // [36800][256] bf16
  u16* ffh = (u16*)S4;                  // [36800][1024] bf16 (75.4 MB)
  float* outp = (float*)d_out;

  // ---- pack weights / inputs to bf16 (every call; no cached state) ----
  k_pack_convw<<<768, 256, 0, stream>>>(conv_w, Wc);
  k_tobf16<<<768, 256, 0, stream>>>(qkv_w, Wqkv, 768 * 256);
  k_tobf16<<<256, 256, 0, stream>>>(o_w, Wo, 256 * 256);
  k_tobf16<<<1024, 256, 0, stream>>>(ffp_w, Wff, 1024 * 256);
  k_tobf16<<<1024, 256, 0, stream>>>(ffg_w, Wff + 1024 * 256, 1024 * 256);
  k_tobf16<<<1024, 256, 0, stream>>>(ffo_w, Wffo, 256 * 1024);
  k_make_x0<<<kB * kP + 1, 256, 0, stream>>>(state, X0, zrow);

  // ---- conv (3 dilation partials) + LN1 ----
  k_conv<<<dim3(288, 2, 3), 256, 0, stream>>>(X0, zrow, Wc, conv_b, pd);
  k_add_ln3<<<kRows / 4, 256, 0, stream>>>(state, pd, pd + kPdStride, pd + 2 * kPdStride,
                                           n1_g, n1_b, stF, stB);

  // ---- attention ----
  k_gemm<<<dim3(72, 6), 256, 0, stream>>>(stB, Wqkv, qkv_b, qkvb, kRows, 768, 256, 4, 2);
  k_attn2<<<dim3(9, kH, kB), 256, 0, stream>>>(qkvb, attn_bias, attnout);
  k_gemm<<<dim3(144, 2), 256, 0, stream>>>(attnout, Wo, o_b, oprojb, kRows, 256, 256, 2, 2);
  k_add_ln<<<kRows / 4, 256, 0, stream>>>(stF, oprojb, n2_g, n2_b, stF, stB);

  // ---- FFN ----
  k_ff1<<<dim3(144, 8), 256, 0, stream>>>(stB, Wff, ffp_b, ffg_b, ffh, kRows, 2);
  k_gemm<<<dim3(144, 2), 256, 0, stream>>>(ffh, Wffo, ffo_b, stB, kRows, 256, 1024, 2, 4);
  k_add_ln<<<kRows / 4, 256, 0, stream>>>(stF, stB, n3_g, n3_b, outp, nullptr);
}

// Round 14
// 598.487 us; speedup vs baseline: 1.1542x; 1.1542x over previous
//
#include <hip/hip_runtime.h>
#include <hip/hip_bf16.h>
#include <cstdio>

// ---------------------------------------------------------------------------
// SyndromeTransformerLayer on MI355X.  Round 14: revert to R12 best-known
// (517.8 us) + T5 s_setprio around conv's MFMA cluster.
// R13 lesson: vmcnt counts STORES on CDNA -> C-writes inside a counted-vmcnt
// loop drain the pipeline (k_ff1 fell to 6% MfmaUtil).  Counted loops must
// contain loads only; epilogue stores stay outside (conv) or the kernel uses
// the plain dbuf+syncthreads form (short-K GEMMs).
// conv: R9 depth-2 counted-vmcnt pipeline + setprio(1) around MFMA.
// k_gemm / k_ff1: R8 dbuf stage-early + single __syncthreads.
// k_attn2: R9 synchronous staging.  LN/pack kernels as R12.
// Workspace: 137,527,296 B, phase-overlapped slots.
// ---------------------------------------------------------------------------

typedef __attribute__((ext_vector_type(8))) short s8v;    // 8 bf16 (4 VGPRs)
typedef __attribute__((ext_vector_type(4))) float f32x4;  // MFMA accumulator
typedef unsigned short u16;

constexpr int kB = 64, kS = 575, kD = 256, kH = 8, kP = 576, kFF = 1024;
constexpr int kRows = kB * kS;  // 36800
constexpr float kEps = 1e-5f;
constexpr float kScale = 0.17677669529663687f;  // 1/sqrt(32)
constexpr size_t kPdStride = 9420800;  // u16 elements per conv partial

__device__ __forceinline__ u16 f2b(float f) {
  __hip_bfloat16 h = __float2bfloat16(f);
  return *reinterpret_cast<u16*>(&h);
}
__device__ __forceinline__ void unpack2(unsigned int w, float& lo, float& hi) {
  union { float f; unsigned int u; } a, b;
  a.u = w << 16;
  b.u = w & 0xffff0000u;
  lo = a.f;
  hi = b.f;
}

__device__ __forceinline__ void gll16(const void* g, void* l) {
  __builtin_amdgcn_global_load_lds((const __attribute__((address_space(1))) void*)g,
                                   (__attribute__((address_space(3))) void*)l, 16, 0, 0);
}

// ------------------------------ packing ------------------------------------
// One block per (i,co) pair: reads 2304 contiguous floats (thread ci takes its
// 9), writes wc[tap][co][ci].
__global__ void k_pack_convw(const float* __restrict__ cw, u16* __restrict__ wc) {
  const int blk = blockIdx.x;   // i*256 + co
  const int ci = threadIdx.x;
  const int i = blk >> 8, co = blk & 255;
  const float* src = cw + (size_t)blk * 2304 + ci * 9;
  float v[9];
#pragma unroll
  for (int r = 0; r < 9; ++r) v[r] = src[r];
#pragma unroll
  for (int r = 0; r < 9; ++r)
    wc[(((size_t)(i * 9 + r)) << 16) + (co << 8) + ci] = f2b(v[r]);
}

__global__ void k_tobf16(const float* __restrict__ in, u16* __restrict__ out, int n) {
  int i = blockIdx.x * 256 + threadIdx.x;
  if (i < n) out[i] = f2b(in[i]);
}

// X0[b][p][c]: p=0 is the zero pad row, else state[b][p-1][c], bf16.
// Extra block (bp == kB*kP) writes the 256-element zero row used by k_conv.
__global__ void k_make_x0(const float* __restrict__ state, u16* __restrict__ x0,
                          u16* __restrict__ zrow) {
  int bp = blockIdx.x;  // b*576 + p, or kB*kP for the zero row
  int c = threadIdx.x;
  if (bp == kB * kP) { zrow[c] = 0; return; }
  int p = bp % kP;
  int b = bp / kP;
  float v = (p == 0) ? 0.f : state[((size_t)(b * kS + p - 1)) * kD + c];
  x0[(size_t)bp * kD + c] = f2b(v);
}

// ------------------------------ GEMM (BK=64, dbuf stage-early) -------------
// C[M][N] = A[M][K](bf16) @ Bw[N][K]^T(bf16) + bias[N], bf16 out.
// 128x128 tile, BK=64, double-buffered LDS, stage-early + 1 sync/step.
// Chunk-XOR swizzle: source chunk (lane&7)^(lane>>3); ds_read XORs back.
// N mult of 128, K mult of 64; M guarded.
__global__ __launch_bounds__(256) void k_gemm(const u16* __restrict__ A,
                                              const u16* __restrict__ Bw,
                                              const float* __restrict__ bias,
                                              u16* __restrict__ Cb,
                                              int M, int N, int K) {
  __shared__ u16 As[2][8192];  // [128][64] x2
  __shared__ u16 Bs[2][8192];
  const int t = threadIdx.x;
  const int wave = t >> 6, lane = t & 63;
  const int wm = wave >> 1, wn = wave & 1;
  const int lr = lane & 15, lk = lane >> 4;
  const int m0 = blockIdx.x * 128, n0 = blockIdx.y * 128;
  const int lrow = lane >> 3;                // 0..7
  const int swzk = ((lane & 7) ^ lrow) * 8;  // swizzled source chunk (u16)
  const u16 *ga[4], *gb[4];
#pragma unroll
  for (int i = 0; i < 4; ++i) {
    int r = 8 * wave + lrow + 32 * i;
    int ra = m0 + r;
    if (ra > M - 1) ra = M - 1;  // clamp: garbage rows are never stored
    ga[i] = A + (size_t)ra * K + swzk;
    gb[i] = Bw + (size_t)(n0 + r) * K + swzk;
  }
  auto stage = [&](int kt, int buf) {
#pragma unroll
    for (int i = 0; i < 4; ++i) {
      gll16(ga[i] + kt, &As[buf][i * 2048 + wave * 512]);
      gll16(gb[i] + kt, &Bs[buf][i * 2048 + wave * 512]);
    }
  };
  f32x4 acc[4][4] = {};
  stage(0, 0);
  __syncthreads();
  const int NT = K >> 6;
  for (int s = 0; s < NT; ++s) {
    const int cur = s & 1;
    if (s + 1 < NT) stage((s + 1) << 6, cur ^ 1);  // prefetch overlaps MFMA
    s8v af[2][4], bfr[2][4];
#pragma unroll
    for (int kk = 0; kk < 2; ++kk)
#pragma unroll
      for (int i = 0; i < 4; ++i) {
        const int rA = wm * 64 + i * 16 + lr;
        const int rB = wn * 64 + i * 16 + lr;
        af[kk][i] = *(const s8v*)(&As[cur][rA * 64 + ((kk * 32 + lk * 8) ^ ((rA & 7) << 3))]);
        bfr[kk][i] = *(const s8v*)(&Bs[cur][rB * 64 + ((kk * 32 + lk * 8) ^ ((rB & 7) << 3))]);
      }
#pragma unroll
    for (int kk = 0; kk < 2; ++kk)
#pragma unroll
      for (int i = 0; i < 4; ++i)
#pragma unroll
        for (int j = 0; j < 4; ++j)
          acc[i][j] = __builtin_amdgcn_mfma_f32_16x16x32_bf16(af[kk][i], bfr[kk][j], acc[i][j], 0, 0, 0);
    __syncthreads();  // drains prefetch + orders reads before next overwrite
  }
#pragma unroll
  for (int i = 0; i < 4; ++i) {
    const int rbase = m0 + wm * 64 + i * 16 + lk * 4;
#pragma unroll
    for (int j = 0; j < 4; ++j) {
      const int col = n0 + wn * 64 + j * 16 + lr;
      const float bv = bias[col];
#pragma unroll
      for (int q = 0; q < 4; ++q) {
        int r = rbase + q;
        if (r < M) Cb[(size_t)r * N + col] = f2b(acc[i][j][q] + bv);
      }
    }
  }
}

// ------------------------------ FF1 + fused sigmoid gate -------------------
// H[r][c] = (A@Wff[c]^T + pb[c]) * sigmoid(A@Wff[1024+c]^T + gb[c]).
// BK=32, double-buffered (48 KB), stage-early + 1 sync/step, chunk-XOR
// swizzle (4 chunks/row): source chunk (t&3)^((t>>2)&3), read XOR (row&3)<<3.
__global__ __launch_bounds__(256) void k_ff1(const u16* __restrict__ A,
                                             const u16* __restrict__ Wf,
                                             const float* __restrict__ pb,
                                             const float* __restrict__ gb,
                                             u16* __restrict__ H, int M) {
  __shared__ u16 As[2][4096];
  __shared__ u16 Bp[2][4096];
  __shared__ u16 Bg[2][4096];
  const int t = threadIdx.x;
  const int wave = t >> 6;
  const int wm = wave >> 1, wn = wave & 1;
  const int lr = t & 15, lk = (t & 63) >> 4;
  const int m0 = blockIdx.x * 128, n0 = blockIdx.y * 128;
  int ra = m0 + (t >> 2);
  int rb = ra + 64;
  if (ra > M - 1) ra = M - 1;
  if (rb > M - 1) rb = M - 1;
  const int koff = (((t & 3) ^ ((t >> 2) & 3)) * 8);  // swizzled source chunk
  const u16* gA0 = A + (size_t)ra * kD + koff;
  const u16* gA1 = A + (size_t)rb * kD + koff;
  const u16* gP0 = Wf + (size_t)(n0 + (t >> 2)) * kD + koff;
  const u16* gP1 = gP0 + (size_t)64 * kD;
  const u16* gG0 = gP0 + (size_t)1024 * kD;
  const u16* gG1 = gP1 + (size_t)1024 * kD;
  auto stage = [&](int kt, int buf) {
    gll16(gA0 + kt, &As[buf][wave * 512]);
    gll16(gA1 + kt, &As[buf][2048 + wave * 512]);
    gll16(gP0 + kt, &Bp[buf][wave * 512]);
    gll16(gP1 + kt, &Bp[buf][2048 + wave * 512]);
    gll16(gG0 + kt, &Bg[buf][wave * 512]);
    gll16(gG1 + kt, &Bg[buf][2048 + wave * 512]);
  };
  f32x4 ap[4][4] = {};
  f32x4 ag[4][4] = {};
  stage(0, 0);
  __syncthreads();
  for (int s = 0; s < 8; ++s) {
    const int cur = s & 1;
    if (s < 7) stage((s + 1) << 5, cur ^ 1);
    s8v af[4], bp4[4], bg4[4];
#pragma unroll
    for (int i = 0; i < 4; ++i) {
      const int rA = wm * 64 + i * 16 + lr;
      const int rB = wn * 64 + i * 16 + lr;
      const int oA = rA * 32 + ((lk * 8) ^ ((rA & 3) << 3));
      const int oB = rB * 32 + ((lk * 8) ^ ((rB & 3) << 3));
      af[i] = *(const s8v*)(&As[cur][oA]);
      bp4[i] = *(const s8v*)(&Bp[cur][oB]);
      bg4[i] = *(const s8v*)(&Bg[cur][oB]);
    }
#pragma unroll
    for (int i = 0; i < 4; ++i)
#pragma unroll
      for (int j = 0; j < 4; ++j) {
        ap[i][j] = __builtin_amdgcn_mfma_f32_16x16x32_bf16(af[i], bp4[j], ap[i][j], 0, 0, 0);
        ag[i][j] = __builtin_amdgcn_mfma_f32_16x16x32_bf16(af[i], bg4[j], ag[i][j], 0, 0, 0);
      }
    __syncthreads();
  }
#pragma unroll
  for (int i = 0; i < 4; ++i) {
    const int rbase = m0 + wm * 64 + i * 16 + lk * 4;
#pragma unroll
    for (int j = 0; j < 4; ++j) {
      const int col = n0 + wn * 64 + j * 16 + lr;
      const float pbv = pb[col], gbv = gb[col];
#pragma unroll
      for (int q = 0; q < 4; ++q) {
        int r = rbase + q;
        if (r < M) {
          float p = ap[i][j][q] + pbv;
          float g = ag[i][j][q] + gbv;
          H[(size_t)r * kFF + col] = f2b(p * (1.f / (1.f + __expf(-g))));
        }
      }
    }
  }
}

// ------------------------------ conv (counted-vmcnt pipeline + T5) ---------
__global__ __launch_bounds__(256) void k_conv(const u16* __restrict__ X0,
                                              const u16* __restrict__ zrow,
                                              const u16* __restrict__ Wc,
                                              const float* __restrict__ cb,
                                              u16* __restrict__ pd) {
  __shared__ u16 As[2][8192];  // [128][64] x2
  __shared__ u16 Bs[2][8192];
  const int t = threadIdx.x;
  const int wave = t >> 6, lane = t & 63;
  const int wm = wave >> 1, wn = wave & 1;
  const int lr = lane & 15, lk = lane >> 4;
  const int m0 = blockIdx.x * 128;
  const int n0 = blockIdx.y * 128;
  const int di = blockIdx.z;
  const int dil = 1 << di;
  const int lrow = lane >> 3;
  const int swzk = ((lane & 7) ^ lrow) * 8;
  const u16* Wd = Wc + ((size_t)di * 9 << 16);
  int py[4], px[4];
  const u16* xrow[4];
  const u16* gw[4];
#pragma unroll
  for (int i = 0; i < 4; ++i) {
    int r = 8 * wave + lrow + 32 * i;
    int m = m0 + r;                 // 0..36863
    int bbv = m / 576;
    int p = m - bbv * 576;
    py[i] = p / 24;
    px[i] = p - py[i] * 24;
    xrow[i] = X0 + (((size_t)(bbv * kP)) << 8) + swzk;
    gw[i] = Wd + (size_t)(n0 + r) * kD + swzk;
  }
  const u16* S0[4];
  const u16* S1[4];
  auto csrc = [&](const u16** dst, int dyv, int dxv) {
#pragma unroll
    for (int i = 0; i < 4; ++i) {
      const int ny = py[i] + dyv, nx = px[i] + dxv;
      const bool v = ((unsigned)ny < 24u) & ((unsigned)nx < 24u);
      dst[i] = v ? xrow[i] + ((ny * 24 + nx) << 8) : zrow + swzk;
    }
  };
  auto stage = [&](const u16* const* S, size_t woff, int kc, int buf) {
#pragma unroll
    for (int i = 0; i < 4; ++i) {
      gll16(S[i] + kc, &As[buf][i * 2048 + wave * 512]);
      gll16(gw[i] + woff + kc, &Bs[buf][i * 2048 + wave * 512]);
    }
  };
  f32x4 acc[4][4] = {};
  csrc(S0, -dil, -dil);   // tap 0
  stage(S0, 0, 0, 0);     // step 0 -> buf 0
  stage(S0, 0, 64, 1);    // step 1 -> buf 1
  for (int tap = 0; tap < 9; ++tap) {
    if (tap < 8) {
      const int tn = tap + 1;
      csrc(S1, (tn / 3 - 1) * dil, (tn % 3 - 1) * dil);
    }
    const size_t woff = (size_t)tap << 16;
#pragma unroll
    for (int c = 0; c < 4; ++c) {
      const int buf = c & 1;  // step s = tap*4+c; s&1 == c&1
      if (c == 3 && tap == 8) {
        asm volatile("s_waitcnt vmcnt(0)" ::: "memory");
      } else {
        asm volatile("s_waitcnt vmcnt(8)" ::: "memory");
      }
      __builtin_amdgcn_s_barrier();
      s8v af[2][4], bfr[2][4];
#pragma unroll
      for (int kk = 0; kk < 2; ++kk)
#pragma unroll
        for (int ii = 0; ii < 4; ++ii) {
          const int rA = wm * 64 + ii * 16 + lr;
          const int rB = wn * 64 + ii * 16 + lr;
          af[kk][ii] = *(const s8v*)(&As[buf][rA * 64 + ((kk * 32 + lk * 8) ^ ((rA & 7) << 3))]);
          bfr[kk][ii] = *(const s8v*)(&Bs[buf][rB * 64 + ((kk * 32 + lk * 8) ^ ((rB & 7) << 3))]);
        }
      __builtin_amdgcn_s_setprio(1);  // T5: favor MFMA-entering waves
#pragma unroll
      for (int kk = 0; kk < 2; ++kk)
#pragma unroll
        for (int ii = 0; ii < 4; ++ii)
#pragma unroll
          for (int jj = 0; jj < 4; ++jj)
            acc[ii][jj] = __builtin_amdgcn_mfma_f32_16x16x32_bf16(af[kk][ii], bfr[kk][jj], acc[ii][jj], 0, 0, 0);
      __builtin_amdgcn_s_setprio(0);
      __builtin_amdgcn_s_barrier();
      if (c == 0) {
        stage(S0, woff, 128, buf);
      } else if (c == 1) {
        stage(S0, woff, 192, buf);
      } else if (c == 2) {
        if (tap < 8) stage(S1, woff + 65536, 0, buf);
      } else {
        if (tap < 8) stage(S1, woff + 65536, 64, buf);
      }
    }
#pragma unroll
    for (int i = 0; i < 4; ++i) S0[i] = S1[i];
  }
  u16* pdo = pd + (size_t)di * kPdStride;
#pragma unroll
  for (int i2 = 0; i2 < 4; ++i2) {
    const int mbase = m0 + wm * 64 + i2 * 16 + lk * 4;
#pragma unroll
    for (int j = 0; j < 4; ++j) {
      const int col = n0 + wn * 64 + j * 16 + lr;
      const float bv = cb[di * kD + col];
#pragma unroll
      for (int q = 0; q < 4; ++q) {
        const int m = mbase + q;
        const int b2 = m / 576;
        const int p = m - b2 * 576;
        if (p >= 1)
          pdo[((size_t)(b2 * kS + p - 1) << 8) + col] = f2b(acc[i2][j][q] + bv);
      }
    }
  }
}

// ------------------------------ attention (MFMA flash, R9 version) ---------
// Reference reshape quirk: q.reshape(b,h,s,hd) on (b,s,256) means head h, pos s'
// = contiguous 32 elems at flat offset h*575*32 + s'*32 of the q block.
// Block: 4 waves, 64 q-rows; K-loop over 575 keys in 9 tiles of 64 (masked).
__global__ __launch_bounds__(256) void k_attn2(const u16* __restrict__ qkv,
                                               const float* __restrict__ bias,
                                               u16* __restrict__ outp) {
  __shared__ u16 KsS[2][2048];  // [64 keys][32 d], swizzled
  __shared__ u16 VtS[2][2048];  // [32 d][64 keys], swizzled
  __shared__ u16 PsS[4][1024];  // per-wave [16 q][64 keys], swizzled
  const int qt = blockIdx.x, h = blockIdx.y, b = blockIdx.z;
  const int tid = threadIdx.x;
  const int w = tid >> 6, lane = tid & 63;
  const int lg = lane >> 4, lr = lane & 15;
  const int q0 = qt * 64;
  const int qrow_a = q0 + w * 16 + lr;
  const int qrow_ac = qrow_a < kS ? qrow_a : kS - 1;
  s8v qf;
  {
    int F = h * (kS * 32) + qrow_ac * 32 + lg * 8;
    qf = *(const s8v*)(qkv + ((size_t)(b * kS + (F >> 8))) * 768 + (F & 255));
  }
  const int trel = tid >> 2;
  const int dcol = (tid & 3) * 8;
  float mrun[4], lsum[4];
#pragma unroll
  for (int r = 0; r < 4; ++r) { mrun[r] = -1e30f; lsum[r] = 0.f; }
  f32x4 o0 = {0.f, 0.f, 0.f, 0.f}, o1 = {0.f, 0.f, 0.f, 0.f};
  const f32x4 zf = {0.f, 0.f, 0.f, 0.f};
  const int qrow_s = q0 + w * 16 + lg * 4;  // +r
  const size_t kvrowbase = (size_t)(b * kS) * 768;

  for (int kt = 0; kt < 9; ++kt) {
    const int t0 = kt * 64;
    const int buf = kt & 1;
    {
      const int tg = t0 + trel;
      const bool tv = tg < kS;
      const int tcl = tv ? tg : kS - 1;
      const int Fk = h * (kS * 32) + tcl * 32 + dcol;
      const u16* kp = qkv + kvrowbase + (size_t)(Fk >> 8) * 768 + 256 + (Fk & 255);
      uint4 kd = {0, 0, 0, 0}, vd = {0, 0, 0, 0};
      if (tv) {
        kd = *(const uint4*)kp;
        vd = *(const uint4*)(kp + 256);
      }
      *(uint4*)&KsS[buf][trel * 32 + (dcol ^ ((trel & 3) << 3))] = kd;
      union { uint4 u4; u16 us[8]; } vu;
      vu.u4 = vd;
#pragma unroll
      for (int j = 0; j < 8; ++j) {
        const int d = dcol + j;
        VtS[buf][d * 64 + (trel ^ ((d & 7) << 3))] = vu.us[j];
      }
    }
    float bv[4][4];  // [j key-subtile][r q-row]
#pragma unroll
    for (int r = 0; r < 4; ++r) {
      const int qr = qrow_s + r;
      const float* bp = bias + ((size_t)h * kS + (qr < kS ? qr : kS - 1)) * kS;
#pragma unroll
      for (int j = 0; j < 4; ++j) {
        const int tg = t0 + j * 16 + lr;
        bv[j][r] = (tg < kS) ? bp[tg] : -1e30f;
      }
    }
    __syncthreads();
    f32x4 sc[4];
#pragma unroll
    for (int j = 0; j < 4; ++j) {
      const int krow = j * 16 + lr;
      s8v kf = *(const s8v*)&KsS[buf][krow * 32 + ((lg * 8) ^ ((krow & 3) << 3))];
      sc[j] = __builtin_amdgcn_mfma_f32_16x16x32_bf16(qf, kf, zf, 0, 0, 0);
    }
#pragma unroll
    for (int r = 0; r < 4; ++r) {
      float s4[4];
      float sm = -1e30f;
#pragma unroll
      for (int j = 0; j < 4; ++j) {
        s4[j] = fmaf(sc[j][r], kScale, bv[j][r]);
        sm = fmaxf(sm, s4[j]);
      }
      sm = fmaxf(sm, __shfl_xor(sm, 1));
      sm = fmaxf(sm, __shfl_xor(sm, 2));
      sm = fmaxf(sm, __shfl_xor(sm, 4));
      sm = fmaxf(sm, __shfl_xor(sm, 8));
      const float nm = fmaxf(mrun[r], sm);
      const float corr = __expf(mrun[r] - nm);
      mrun[r] = nm;
      float psum = 0.f;
      const int prow = lg * 4 + r;
#pragma unroll
      for (int j = 0; j < 4; ++j) {
        const float p = __expf(s4[j] - nm);
        psum += p;
        PsS[w][prow * 64 + ((j * 16 + lr) ^ ((prow & 7) << 3))] = f2b(p);
      }
      lsum[r] = fmaf(lsum[r], corr, psum);
      o0[r] *= corr;
      o1[r] *= corr;
    }
#pragma unroll
    for (int c = 0; c < 2; ++c) {
      const int pcol = c * 32 + lg * 8;
      s8v pf = *(const s8v*)&PsS[w][lr * 64 + (pcol ^ ((lr & 7) << 3))];
      s8v vf0 = *(const s8v*)&VtS[buf][lr * 64 + (pcol ^ ((lr & 7) << 3))];
      s8v vf1 = *(const s8v*)&VtS[buf][(16 + lr) * 64 + (pcol ^ (((16 + lr) & 7) << 3))];
      o0 = __builtin_amdgcn_mfma_f32_16x16x32_bf16(pf, vf0, o0, 0, 0, 0);
      o1 = __builtin_amdgcn_mfma_f32_16x16x32_bf16(pf, vf1, o1, 0, 0, 0);
    }
  }
#pragma unroll
  for (int r = 0; r < 4; ++r) {
    float lt = lsum[r];
    lt += __shfl_xor(lt, 1);
    lt += __shfl_xor(lt, 2);
    lt += __shfl_xor(lt, 4);
    lt += __shfl_xor(lt, 8);
    const float inv = 1.f / lt;
    const int qr = qrow_s + r;
    if (qr < kS) {
      u16* op = outp + ((size_t)(b * kS + qr)) * kD + h * 32;
      op[lr] = f2b(o0[r] * inv);
      op[16 + lr] = f2b(o1[r] * inv);
    }
  }
}

// ------------------------------ add + LayerNorm ----------------------------
__global__ __launch_bounds__(256) void k_add_ln(const float* __restrict__ xa,
                                                const u16* __restrict__ xb,
                                                const float* __restrict__ g,
                                                const float* __restrict__ be,
                                                float* __restrict__ of, u16* __restrict__ ob) {
  const int wave = threadIdx.x >> 6, lane = threadIdx.x & 63;
  const int row = blockIdx.x * 4 + wave;
  const float4 a = ((const float4*)(xa + (size_t)row * kD))[lane];
  uint2 bw = ((const uint2*)(xb + (size_t)row * kD))[lane];
  float b0, b1, b2, b3;
  unpack2(bw.x, b0, b1);
  unpack2(bw.y, b2, b3);
  float x0 = a.x + b0, x1 = a.y + b1, x2 = a.z + b2, x3 = a.w + b3;
  float sum = x0 + x1 + x2 + x3;
  float sq = fmaf(x0, x0, fmaf(x1, x1, fmaf(x2, x2, x3 * x3)));
  for (int off = 1; off < 64; off <<= 1) {
    sum += __shfl_xor(sum, off);
    sq += __shfl_xor(sq, off);
  }
  const float mean = sum * (1.f / 256.f);
  const float var = sq * (1.f / 256.f) - mean * mean;
  const float rs = rsqrtf(var + kEps);
  const float4 gg = ((const float4*)g)[lane];
  const float4 bt = ((const float4*)be)[lane];
  float y0 = (x0 - mean) * rs * gg.x + bt.x;
  float y1 = (x1 - mean) * rs * gg.y + bt.y;
  float y2 = (x2 - mean) * rs * gg.z + bt.z;
  float y3 = (x3 - mean) * rs * gg.w + bt.w;
  float4 yo = {y0, y1, y2, y3};
  ((float4*)(of + (size_t)row * kD))[lane] = yo;
  if (ob) {
    u16* po = ob + (size_t)row * kD + lane * 4;
    po[0] = f2b(y0); po[1] = f2b(y1); po[2] = f2b(y2); po[3] = f2b(y3);
  }
}

// add+LN over state + three bf16 conv partials (LN1).
__global__ __launch_bounds__(256) void k_add_ln3(const float* __restrict__ xa,
                                                 const u16* __restrict__ pa,
                                                 const u16* __restrict__ pbq,
                                                 const u16* __restrict__ pc,
                                                 const float* __restrict__ g,
                                                 const float* __restrict__ be,
                                                 float* __restrict__ of, u16* __restrict__ ob) {
  const int wave = threadIdx.x >> 6, lane = threadIdx.x & 63;
  const int row = blockIdx.x * 4 + wave;
  const size_t base = (size_t)row * kD;
  const float4 a = ((const float4*)(xa + base))[lane];
  uint2 w0 = ((const uint2*)(pa + base))[lane];
  uint2 w1 = ((const uint2*)(pbq + base))[lane];
  uint2 w2 = ((const uint2*)(pc + base))[lane];
  float a0, a1, a2, a3, c0, c1, c2, c3, d0, d1, d2, d3;
  unpack2(w0.x, a0, a1); unpack2(w0.y, a2, a3);
  unpack2(w1.x, c0, c1); unpack2(w1.y, c2, c3);
  unpack2(w2.x, d0, d1); unpack2(w2.y, d2, d3);
  float x0 = a.x + a0 + c0 + d0, x1 = a.y + a1 + c1 + d1;
  float x2 = a.z + a2 + c2 + d2, x3 = a.w + a3 + c3 + d3;
  float sum = x0 + x1 + x2 + x3;
  float sq = fmaf(x0, x0, fmaf(x1, x1, fmaf(x2, x2, x3 * x3)));
  for (int off = 1; off < 64; off <<= 1) {
    sum += __shfl_xor(sum, off);
    sq += __shfl_xor(sq, off);
  }
  const float mean = sum * (1.f / 256.f);
  const float var = sq * (1.f / 256.f) - mean * mean;
  const float rs = rsqrtf(var + kEps);
  const float4 gg = ((const float4*)g)[lane];
  const float4 bt = ((const float4*)be)[lane];
  float y0 = (x0 - mean) * rs * gg.x + bt.x;
  float y1 = (x1 - mean) * rs * gg.y + bt.y;
  float y2 = (x2 - mean) * rs * gg.z + bt.z;
  float y3 = (x3 - mean) * rs * gg.w + bt.w;
  float4 yo = {y0, y1, y2, y3};
  ((float4*)(of + base))[lane] = yo;
  u16* po = ob + base + lane * 4;
  po[0] = f2b(y0); po[1] = f2b(y1); po[2] = f2b(y2); po[3] = f2b(y3);
}

// ------------------------------ launch -------------------------------------
extern "C" void kernel_launch(void* const* d_in, const int* in_sizes, int n_in,
                              void* d_out, int out_size, void* d_ws, size_t ws_size,
                              hipStream_t stream) {
  const float* state = (const float*)d_in[0];
  const float* conv_w = (const float*)d_in[1];
  const float* conv_b = (const float*)d_in[2];
  const float* qkv_w = (const float*)d_in[3];
  const float* qkv_b = (const float*)d_in[4];
  const float* o_w = (const float*)d_in[5];
  const float* o_b = (const float*)d_in[6];
  const float* attn_bias = (const float*)d_in[7];
  const float* ffp_w = (const float*)d_in[8];
  const float* ffp_b = (const float*)d_in[9];
  const float* ffg_w = (const float*)d_in[10];
  const float* ffg_b = (const float*)d_in[11];
  const float* ffo_w = (const float*)d_in[12];
  const float* ffo_b = (const float*)d_in[13];
  const float* n1_g = (const float*)d_in[14];
  const float* n1_b = (const float*)d_in[15];
  const float* n2_g = (const float*)d_in[16];
  const float* n2_b = (const float*)d_in[17];
  const float* n3_g = (const float*)d_in[18];
  const float* n3_b = (const float*)d_in[19];

  // ---- workspace layout: 137,527,296 bytes, phase-overlapped ----
  constexpr size_t kWsNeed = 137527296;
  if (ws_size < kWsNeed) {
    fprintf(stderr, "[kernel] ws_size=%zu < need=%zu\n", ws_size, kWsNeed);
    return;
  }
  char* ws = (char*)d_ws;
  u16* Wc = (u16*)(ws + 0);             // [27][256][256] bf16  (3,538,944 B)
  u16* Wqkv = (u16*)(ws + 3538944);     // [768][256]
  u16* Wo = (u16*)(ws + 3932160);       // [256][256]
  u16* Wff = (u16*)(ws + 4063232);      // [2048][256] (proj;gate)
  u16* Wffo = (u16*)(ws + 5111808);     // [256][1024]  (ends 5,636,096)
  float* stF = (float*)(ws + 5636096);  // [36800][256] f32 state (37,683,200 B)
  u16* stB = (u16*)(ws + 43319296);     // [36800][256] bf16 (18,841,600 B)
  char* S4 = ws + 62160896;             // 75,366,400 B shared slot
  // conv phase overlays:
  u16* X0 = (u16*)(ws + 5636096);       // in stF slot: [64][576][256] bf16
  u16* zrow = (u16*)(ws + 43319296);    // in stB slot: 256 zeros
  u16* pd = (u16*)S4;                   // 3 partials, stride kPdStride u16
  // attn/ffn phase overlays:
  u16* qkvb = (u16*)S4;                 // [36800][768] bf16 (56.5 MB)
  u16* attnout = (u16*)(S4 + 56524800); // [36800][256] bf16
  u16* oprojb = (u16*)S4;               // [36800][256] bf16
  u16* ffh = (u16*)S4;                  // [36800][1024] bf16 (75.4 MB)
  float* outp = (float*)d_out;

  // ---- pack weights / inputs to bf16 (every call; no cached state) ----
  k_pack_convw<<<768, 256, 0, stream>>>(conv_w, Wc);
  k_tobf16<<<768, 256, 0, stream>>>(qkv_w, Wqkv, 768 * 256);
  k_tobf16<<<256, 256, 0, stream>>>(o_w, Wo, 256 * 256);
  k_tobf16<<<1024, 256, 0, stream>>>(ffp_w, Wff, 1024 * 256);
  k_tobf16<<<1024, 256, 0, stream>>>(ffg_w, Wff + 1024 * 256, 1024 * 256);
  k_tobf16<<<1024, 256, 0, stream>>>(ffo_w, Wffo, 256 * 1024);
  k_make_x0<<<kB * kP + 1, 256, 0, stream>>>(state, X0, zrow);

  // ---- conv (3 dilation partials) + LN1 ----
  k_conv<<<dim3(288, 2, 3), 256, 0, stream>>>(X0, zrow, Wc, conv_b, pd);
  k_add_ln3<<<kRows / 4, 256, 0, stream>>>(state, pd, pd + kPdStride, pd + 2 * kPdStride,
                                           n1_g, n1_b, stF, stB);

  // ---- attention ----
  k_gemm<<<dim3(288, 6), 256, 0, stream>>>(stB, Wqkv, qkv_b, qkvb, kRows, 768, 256);
  k_attn2<<<dim3(9, kH, kB), 256, 0, stream>>>(qkvb, attn_bias, attnout);
  k_gemm<<<dim3(288, 2), 256, 0, stream>>>(attnout, Wo, o_b, oprojb, kRows, 256, 256);
  k_add_ln<<<kRows / 4, 256, 0, stream>>>(stF, oprojb, n2_g, n2_b, stF, stB);

  // ---- FFN ----
  k_ff1<<<dim3(288, 8), 256, 0, stream>>>(stB, Wff, ffp_b, ffg_b, ffh, kRows);
  k_gemm<<<dim3(288, 2), 256, 0, stream>>>(ffh, Wffo, ffo_b, stB, kRows, 256, 1024);
  k_add_ln<<<kRows / 4, 256, 0, stream>>>(stF, stB, n3_g, n3_b, outp, nullptr);
}

// Round 15
// 515.947 us; speedup vs baseline: 1.3389x; 1.1600x over previous
//
#include <hip/hip_runtime.h>
#include <hip/hip_bf16.h>
#include <cstdio>

// ---------------------------------------------------------------------------
// SyndromeTransformerLayer on MI355X.  Round 15: exact revert to R12
// (best-known 517.8 us).  R14's T5 setprio cost 40 VGPRs (scheduling fence ->
// longer live ranges) and halved conv occupancy; removed.
// conv: R9 depth-2 counted-vmcnt pipeline (155 us, MfmaUtil 37%).
// k_gemm / k_ff1: R8 dbuf stage-early + single __syncthreads.
// k_attn2: R9 synchronous staging.  LN/pack kernels as R12.
// Workspace: 137,527,296 B, phase-overlapped slots.
// ---------------------------------------------------------------------------

typedef __attribute__((ext_vector_type(8))) short s8v;    // 8 bf16 (4 VGPRs)
typedef __attribute__((ext_vector_type(4))) float f32x4;  // MFMA accumulator
typedef unsigned short u16;

constexpr int kB = 64, kS = 575, kD = 256, kH = 8, kP = 576, kFF = 1024;
constexpr int kRows = kB * kS;  // 36800
constexpr float kEps = 1e-5f;
constexpr float kScale = 0.17677669529663687f;  // 1/sqrt(32)
constexpr size_t kPdStride = 9420800;  // u16 elements per conv partial

__device__ __forceinline__ u16 f2b(float f) {
  __hip_bfloat16 h = __float2bfloat16(f);
  return *reinterpret_cast<u16*>(&h);
}
__device__ __forceinline__ void unpack2(unsigned int w, float& lo, float& hi) {
  union { float f; unsigned int u; } a, b;
  a.u = w << 16;
  b.u = w & 0xffff0000u;
  lo = a.f;
  hi = b.f;
}

__device__ __forceinline__ void gll16(const void* g, void* l) {
  __builtin_amdgcn_global_load_lds((const __attribute__((address_space(1))) void*)g,
                                   (__attribute__((address_space(3))) void*)l, 16, 0, 0);
}

// ------------------------------ packing ------------------------------------
// One block per (i,co) pair: reads 2304 contiguous floats (thread ci takes its
// 9), writes wc[tap][co][ci].
__global__ void k_pack_convw(const float* __restrict__ cw, u16* __restrict__ wc) {
  const int blk = blockIdx.x;   // i*256 + co
  const int ci = threadIdx.x;
  const int i = blk >> 8, co = blk & 255;
  const float* src = cw + (size_t)blk * 2304 + ci * 9;
  float v[9];
#pragma unroll
  for (int r = 0; r < 9; ++r) v[r] = src[r];
#pragma unroll
  for (int r = 0; r < 9; ++r)
    wc[(((size_t)(i * 9 + r)) << 16) + (co << 8) + ci] = f2b(v[r]);
}

__global__ void k_tobf16(const float* __restrict__ in, u16* __restrict__ out, int n) {
  int i = blockIdx.x * 256 + threadIdx.x;
  if (i < n) out[i] = f2b(in[i]);
}

// X0[b][p][c]: p=0 is the zero pad row, else state[b][p-1][c], bf16.
// Extra block (bp == kB*kP) writes the 256-element zero row used by k_conv.
__global__ void k_make_x0(const float* __restrict__ state, u16* __restrict__ x0,
                          u16* __restrict__ zrow) {
  int bp = blockIdx.x;  // b*576 + p, or kB*kP for the zero row
  int c = threadIdx.x;
  if (bp == kB * kP) { zrow[c] = 0; return; }
  int p = bp % kP;
  int b = bp / kP;
  float v = (p == 0) ? 0.f : state[((size_t)(b * kS + p - 1)) * kD + c];
  x0[(size_t)bp * kD + c] = f2b(v);
}

// ------------------------------ GEMM (BK=64, dbuf stage-early) -------------
// C[M][N] = A[M][K](bf16) @ Bw[N][K]^T(bf16) + bias[N], bf16 out.
// 128x128 tile, BK=64, double-buffered LDS, stage-early + 1 sync/step.
// Chunk-XOR swizzle: source chunk (lane&7)^(lane>>3); ds_read XORs back.
// N mult of 128, K mult of 64; M guarded.
__global__ __launch_bounds__(256) void k_gemm(const u16* __restrict__ A,
                                              const u16* __restrict__ Bw,
                                              const float* __restrict__ bias,
                                              u16* __restrict__ Cb,
                                              int M, int N, int K) {
  __shared__ u16 As[2][8192];  // [128][64] x2
  __shared__ u16 Bs[2][8192];
  const int t = threadIdx.x;
  const int wave = t >> 6, lane = t & 63;
  const int wm = wave >> 1, wn = wave & 1;
  const int lr = lane & 15, lk = lane >> 4;
  const int m0 = blockIdx.x * 128, n0 = blockIdx.y * 128;
  const int lrow = lane >> 3;                // 0..7
  const int swzk = ((lane & 7) ^ lrow) * 8;  // swizzled source chunk (u16)
  const u16 *ga[4], *gb[4];
#pragma unroll
  for (int i = 0; i < 4; ++i) {
    int r = 8 * wave + lrow + 32 * i;
    int ra = m0 + r;
    if (ra > M - 1) ra = M - 1;  // clamp: garbage rows are never stored
    ga[i] = A + (size_t)ra * K + swzk;
    gb[i] = Bw + (size_t)(n0 + r) * K + swzk;
  }
  auto stage = [&](int kt, int buf) {
#pragma unroll
    for (int i = 0; i < 4; ++i) {
      gll16(ga[i] + kt, &As[buf][i * 2048 + wave * 512]);
      gll16(gb[i] + kt, &Bs[buf][i * 2048 + wave * 512]);
    }
  };
  f32x4 acc[4][4] = {};
  stage(0, 0);
  __syncthreads();
  const int NT = K >> 6;
  for (int s = 0; s < NT; ++s) {
    const int cur = s & 1;
    if (s + 1 < NT) stage((s + 1) << 6, cur ^ 1);  // prefetch overlaps MFMA
    s8v af[2][4], bfr[2][4];
#pragma unroll
    for (int kk = 0; kk < 2; ++kk)
#pragma unroll
      for (int i = 0; i < 4; ++i) {
        const int rA = wm * 64 + i * 16 + lr;
        const int rB = wn * 64 + i * 16 + lr;
        af[kk][i] = *(const s8v*)(&As[cur][rA * 64 + ((kk * 32 + lk * 8) ^ ((rA & 7) << 3))]);
        bfr[kk][i] = *(const s8v*)(&Bs[cur][rB * 64 + ((kk * 32 + lk * 8) ^ ((rB & 7) << 3))]);
      }
#pragma unroll
    for (int kk = 0; kk < 2; ++kk)
#pragma unroll
      for (int i = 0; i < 4; ++i)
#pragma unroll
        for (int j = 0; j < 4; ++j)
          acc[i][j] = __builtin_amdgcn_mfma_f32_16x16x32_bf16(af[kk][i], bfr[kk][j], acc[i][j], 0, 0, 0);
    __syncthreads();  // drains prefetch + orders reads before next overwrite
  }
#pragma unroll
  for (int i = 0; i < 4; ++i) {
    const int rbase = m0 + wm * 64 + i * 16 + lk * 4;
#pragma unroll
    for (int j = 0; j < 4; ++j) {
      const int col = n0 + wn * 64 + j * 16 + lr;
      const float bv = bias[col];
#pragma unroll
      for (int q = 0; q < 4; ++q) {
        int r = rbase + q;
        if (r < M) Cb[(size_t)r * N + col] = f2b(acc[i][j][q] + bv);
      }
    }
  }
}

// ------------------------------ FF1 + fused sigmoid gate -------------------
// H[r][c] = (A@Wff[c]^T + pb[c]) * sigmoid(A@Wff[1024+c]^T + gb[c]).
// BK=32, double-buffered (48 KB), stage-early + 1 sync/step, chunk-XOR
// swizzle (4 chunks/row): source chunk (t&3)^((t>>2)&3), read XOR (row&3)<<3.
__global__ __launch_bounds__(256) void k_ff1(const u16* __restrict__ A,
                                             const u16* __restrict__ Wf,
                                             const float* __restrict__ pb,
                                             const float* __restrict__ gb,
                                             u16* __restrict__ H, int M) {
  __shared__ u16 As[2][4096];
  __shared__ u16 Bp[2][4096];
  __shared__ u16 Bg[2][4096];
  const int t = threadIdx.x;
  const int wave = t >> 6;
  const int wm = wave >> 1, wn = wave & 1;
  const int lr = t & 15, lk = (t & 63) >> 4;
  const int m0 = blockIdx.x * 128, n0 = blockIdx.y * 128;
  int ra = m0 + (t >> 2);
  int rb = ra + 64;
  if (ra > M - 1) ra = M - 1;
  if (rb > M - 1) rb = M - 1;
  const int koff = (((t & 3) ^ ((t >> 2) & 3)) * 8);  // swizzled source chunk
  const u16* gA0 = A + (size_t)ra * kD + koff;
  const u16* gA1 = A + (size_t)rb * kD + koff;
  const u16* gP0 = Wf + (size_t)(n0 + (t >> 2)) * kD + koff;
  const u16* gP1 = gP0 + (size_t)64 * kD;
  const u16* gG0 = gP0 + (size_t)1024 * kD;
  const u16* gG1 = gP1 + (size_t)1024 * kD;
  auto stage = [&](int kt, int buf) {
    gll16(gA0 + kt, &As[buf][wave * 512]);
    gll16(gA1 + kt, &As[buf][2048 + wave * 512]);
    gll16(gP0 + kt, &Bp[buf][wave * 512]);
    gll16(gP1 + kt, &Bp[buf][2048 + wave * 512]);
    gll16(gG0 + kt, &Bg[buf][wave * 512]);
    gll16(gG1 + kt, &Bg[buf][2048 + wave * 512]);
  };
  f32x4 ap[4][4] = {};
  f32x4 ag[4][4] = {};
  stage(0, 0);
  __syncthreads();
  for (int s = 0; s < 8; ++s) {
    const int cur = s & 1;
    if (s < 7) stage((s + 1) << 5, cur ^ 1);
    s8v af[4], bp4[4], bg4[4];
#pragma unroll
    for (int i = 0; i < 4; ++i) {
      const int rA = wm * 64 + i * 16 + lr;
      const int rB = wn * 64 + i * 16 + lr;
      const int oA = rA * 32 + ((lk * 8) ^ ((rA & 3) << 3));
      const int oB = rB * 32 + ((lk * 8) ^ ((rB & 3) << 3));
      af[i] = *(const s8v*)(&As[cur][oA]);
      bp4[i] = *(const s8v*)(&Bp[cur][oB]);
      bg4[i] = *(const s8v*)(&Bg[cur][oB]);
    }
#pragma unroll
    for (int i = 0; i < 4; ++i)
#pragma unroll
      for (int j = 0; j < 4; ++j) {
        ap[i][j] = __builtin_amdgcn_mfma_f32_16x16x32_bf16(af[i], bp4[j], ap[i][j], 0, 0, 0);
        ag[i][j] = __builtin_amdgcn_mfma_f32_16x16x32_bf16(af[i], bg4[j], ag[i][j], 0, 0, 0);
      }
    __syncthreads();
  }
#pragma unroll
  for (int i = 0; i < 4; ++i) {
    const int rbase = m0 + wm * 64 + i * 16 + lk * 4;
#pragma unroll
    for (int j = 0; j < 4; ++j) {
      const int col = n0 + wn * 64 + j * 16 + lr;
      const float pbv = pb[col], gbv = gb[col];
#pragma unroll
      for (int q = 0; q < 4; ++q) {
        int r = rbase + q;
        if (r < M) {
          float p = ap[i][j][q] + pbv;
          float g = ag[i][j][q] + gbv;
          H[(size_t)r * kFF + col] = f2b(p * (1.f / (1.f + __expf(-g))));
        }
      }
    }
  }
}

// ------------------------------ conv (counted-vmcnt pipeline, R9) ----------
__global__ __launch_bounds__(256) void k_conv(const u16* __restrict__ X0,
                                              const u16* __restrict__ zrow,
                                              const u16* __restrict__ Wc,
                                              const float* __restrict__ cb,
                                              u16* __restrict__ pd) {
  __shared__ u16 As[2][8192];  // [128][64] x2
  __shared__ u16 Bs[2][8192];
  const int t = threadIdx.x;
  const int wave = t >> 6, lane = t & 63;
  const int wm = wave >> 1, wn = wave & 1;
  const int lr = lane & 15, lk = lane >> 4;
  const int m0 = blockIdx.x * 128;
  const int n0 = blockIdx.y * 128;
  const int di = blockIdx.z;
  const int dil = 1 << di;
  const int lrow = lane >> 3;
  const int swzk = ((lane & 7) ^ lrow) * 8;
  const u16* Wd = Wc + ((size_t)di * 9 << 16);
  int py[4], px[4];
  const u16* xrow[4];
  const u16* gw[4];
#pragma unroll
  for (int i = 0; i < 4; ++i) {
    int r = 8 * wave + lrow + 32 * i;
    int m = m0 + r;                 // 0..36863
    int bbv = m / 576;
    int p = m - bbv * 576;
    py[i] = p / 24;
    px[i] = p - py[i] * 24;
    xrow[i] = X0 + (((size_t)(bbv * kP)) << 8) + swzk;
    gw[i] = Wd + (size_t)(n0 + r) * kD + swzk;
  }
  const u16* S0[4];
  const u16* S1[4];
  auto csrc = [&](const u16** dst, int dyv, int dxv) {
#pragma unroll
    for (int i = 0; i < 4; ++i) {
      const int ny = py[i] + dyv, nx = px[i] + dxv;
      const bool v = ((unsigned)ny < 24u) & ((unsigned)nx < 24u);
      dst[i] = v ? xrow[i] + ((ny * 24 + nx) << 8) : zrow + swzk;
    }
  };
  auto stage = [&](const u16* const* S, size_t woff, int kc, int buf) {
#pragma unroll
    for (int i = 0; i < 4; ++i) {
      gll16(S[i] + kc, &As[buf][i * 2048 + wave * 512]);
      gll16(gw[i] + woff + kc, &Bs[buf][i * 2048 + wave * 512]);
    }
  };
  f32x4 acc[4][4] = {};
  csrc(S0, -dil, -dil);   // tap 0
  stage(S0, 0, 0, 0);     // step 0 -> buf 0
  stage(S0, 0, 64, 1);    // step 1 -> buf 1
  for (int tap = 0; tap < 9; ++tap) {
    if (tap < 8) {
      const int tn = tap + 1;
      csrc(S1, (tn / 3 - 1) * dil, (tn % 3 - 1) * dil);
    }
    const size_t woff = (size_t)tap << 16;
#pragma unroll
    for (int c = 0; c < 4; ++c) {
      const int buf = c & 1;  // step s = tap*4+c; s&1 == c&1
      if (c == 3 && tap == 8) {
        asm volatile("s_waitcnt vmcnt(0)" ::: "memory");
      } else {
        asm volatile("s_waitcnt vmcnt(8)" ::: "memory");
      }
      __builtin_amdgcn_s_barrier();
      s8v af[2][4], bfr[2][4];
#pragma unroll
      for (int kk = 0; kk < 2; ++kk)
#pragma unroll
        for (int ii = 0; ii < 4; ++ii) {
          const int rA = wm * 64 + ii * 16 + lr;
          const int rB = wn * 64 + ii * 16 + lr;
          af[kk][ii] = *(const s8v*)(&As[buf][rA * 64 + ((kk * 32 + lk * 8) ^ ((rA & 7) << 3))]);
          bfr[kk][ii] = *(const s8v*)(&Bs[buf][rB * 64 + ((kk * 32 + lk * 8) ^ ((rB & 7) << 3))]);
        }
#pragma unroll
      for (int kk = 0; kk < 2; ++kk)
#pragma unroll
        for (int ii = 0; ii < 4; ++ii)
#pragma unroll
          for (int jj = 0; jj < 4; ++jj)
            acc[ii][jj] = __builtin_amdgcn_mfma_f32_16x16x32_bf16(af[kk][ii], bfr[kk][jj], acc[ii][jj], 0, 0, 0);
      __builtin_amdgcn_s_barrier();
      if (c == 0) {
        stage(S0, woff, 128, buf);
      } else if (c == 1) {
        stage(S0, woff, 192, buf);
      } else if (c == 2) {
        if (tap < 8) stage(S1, woff + 65536, 0, buf);
      } else {
        if (tap < 8) stage(S1, woff + 65536, 64, buf);
      }
    }
#pragma unroll
    for (int i = 0; i < 4; ++i) S0[i] = S1[i];
  }
  u16* pdo = pd + (size_t)di * kPdStride;
#pragma unroll
  for (int i2 = 0; i2 < 4; ++i2) {
    const int mbase = m0 + wm * 64 + i2 * 16 + lk * 4;
#pragma unroll
    for (int j = 0; j < 4; ++j) {
      const int col = n0 + wn * 64 + j * 16 + lr;
      const float bv = cb[di * kD + col];
#pragma unroll
      for (int q = 0; q < 4; ++q) {
        const int m = mbase + q;
        const int b2 = m / 576;
        const int p = m - b2 * 576;
        if (p >= 1)
          pdo[((size_t)(b2 * kS + p - 1) << 8) + col] = f2b(acc[i2][j][q] + bv);
      }
    }
  }
}

// ------------------------------ attention (MFMA flash, R9 version) ---------
// Reference reshape quirk: q.reshape(b,h,s,hd) on (b,s,256) means head h, pos s'
// = contiguous 32 elems at flat offset h*575*32 + s'*32 of the q block.
// Block: 4 waves, 64 q-rows; K-loop over 575 keys in 9 tiles of 64 (masked).
__global__ __launch_bounds__(256) void k_attn2(const u16* __restrict__ qkv,
                                               const float* __restrict__ bias,
                                               u16* __restrict__ outp) {
  __shared__ u16 KsS[2][2048];  // [64 keys][32 d], swizzled
  __shared__ u16 VtS[2][2048];  // [32 d][64 keys], swizzled
  __shared__ u16 PsS[4][1024];  // per-wave [16 q][64 keys], swizzled
  const int qt = blockIdx.x, h = blockIdx.y, b = blockIdx.z;
  const int tid = threadIdx.x;
  const int w = tid >> 6, lane = tid & 63;
  const int lg = lane >> 4, lr = lane & 15;
  const int q0 = qt * 64;
  const int qrow_a = q0 + w * 16 + lr;
  const int qrow_ac = qrow_a < kS ? qrow_a : kS - 1;
  s8v qf;
  {
    int F = h * (kS * 32) + qrow_ac * 32 + lg * 8;
    qf = *(const s8v*)(qkv + ((size_t)(b * kS + (F >> 8))) * 768 + (F & 255));
  }
  const int trel = tid >> 2;
  const int dcol = (tid & 3) * 8;
  float mrun[4], lsum[4];
#pragma unroll
  for (int r = 0; r < 4; ++r) { mrun[r] = -1e30f; lsum[r] = 0.f; }
  f32x4 o0 = {0.f, 0.f, 0.f, 0.f}, o1 = {0.f, 0.f, 0.f, 0.f};
  const f32x4 zf = {0.f, 0.f, 0.f, 0.f};
  const int qrow_s = q0 + w * 16 + lg * 4;  // +r
  const size_t kvrowbase = (size_t)(b * kS) * 768;

  for (int kt = 0; kt < 9; ++kt) {
    const int t0 = kt * 64;
    const int buf = kt & 1;
    {
      const int tg = t0 + trel;
      const bool tv = tg < kS;
      const int tcl = tv ? tg : kS - 1;
      const int Fk = h * (kS * 32) + tcl * 32 + dcol;
      const u16* kp = qkv + kvrowbase + (size_t)(Fk >> 8) * 768 + 256 + (Fk & 255);
      uint4 kd = {0, 0, 0, 0}, vd = {0, 0, 0, 0};
      if (tv) {
        kd = *(const uint4*)kp;
        vd = *(const uint4*)(kp + 256);
      }
      *(uint4*)&KsS[buf][trel * 32 + (dcol ^ ((trel & 3) << 3))] = kd;
      union { uint4 u4; u16 us[8]; } vu;
      vu.u4 = vd;
#pragma unroll
      for (int j = 0; j < 8; ++j) {
        const int d = dcol + j;
        VtS[buf][d * 64 + (trel ^ ((d & 7) << 3))] = vu.us[j];
      }
    }
    float bv[4][4];  // [j key-subtile][r q-row]
#pragma unroll
    for (int r = 0; r < 4; ++r) {
      const int qr = qrow_s + r;
      const float* bp = bias + ((size_t)h * kS + (qr < kS ? qr : kS - 1)) * kS;
#pragma unroll
      for (int j = 0; j < 4; ++j) {
        const int tg = t0 + j * 16 + lr;
        bv[j][r] = (tg < kS) ? bp[tg] : -1e30f;
      }
    }
    __syncthreads();
    f32x4 sc[4];
#pragma unroll
    for (int j = 0; j < 4; ++j) {
      const int krow = j * 16 + lr;
      s8v kf = *(const s8v*)&KsS[buf][krow * 32 + ((lg * 8) ^ ((krow & 3) << 3))];
      sc[j] = __builtin_amdgcn_mfma_f32_16x16x32_bf16(qf, kf, zf, 0, 0, 0);
    }
#pragma unroll
    for (int r = 0; r < 4; ++r) {
      float s4[4];
      float sm = -1e30f;
#pragma unroll
      for (int j = 0; j < 4; ++j) {
        s4[j] = fmaf(sc[j][r], kScale, bv[j][r]);
        sm = fmaxf(sm, s4[j]);
      }
      sm = fmaxf(sm, __shfl_xor(sm, 1));
      sm = fmaxf(sm, __shfl_xor(sm, 2));
      sm = fmaxf(sm, __shfl_xor(sm, 4));
      sm = fmaxf(sm, __shfl_xor(sm, 8));
      const float nm = fmaxf(mrun[r], sm);
      const float corr = __expf(mrun[r] - nm);
      mrun[r] = nm;
      float psum = 0.f;
      const int prow = lg * 4 + r;
#pragma unroll
      for (int j = 0; j < 4; ++j) {
        const float p = __expf(s4[j] - nm);
        psum += p;
        PsS[w][prow * 64 + ((j * 16 + lr) ^ ((prow & 7) << 3))] = f2b(p);
      }
      lsum[r] = fmaf(lsum[r], corr, psum);
      o0[r] *= corr;
      o1[r] *= corr;
    }
#pragma unroll
    for (int c = 0; c < 2; ++c) {
      const int pcol = c * 32 + lg * 8;
      s8v pf = *(const s8v*)&PsS[w][lr * 64 + (pcol ^ ((lr & 7) << 3))];
      s8v vf0 = *(const s8v*)&VtS[buf][lr * 64 + (pcol ^ ((lr & 7) << 3))];
      s8v vf1 = *(const s8v*)&VtS[buf][(16 + lr) * 64 + (pcol ^ (((16 + lr) & 7) << 3))];
      o0 = __builtin_amdgcn_mfma_f32_16x16x32_bf16(pf, vf0, o0, 0, 0, 0);
      o1 = __builtin_amdgcn_mfma_f32_16x16x32_bf16(pf, vf1, o1, 0, 0, 0);
    }
  }
#pragma unroll
  for (int r = 0; r < 4; ++r) {
    float lt = lsum[r];
    lt += __shfl_xor(lt, 1);
    lt += __shfl_xor(lt, 2);
    lt += __shfl_xor(lt, 4);
    lt += __shfl_xor(lt, 8);
    const float inv = 1.f / lt;
    const int qr = qrow_s + r;
    if (qr < kS) {
      u16* op = outp + ((size_t)(b * kS + qr)) * kD + h * 32;
      op[lr] = f2b(o0[r] * inv);
      op[16 + lr] = f2b(o1[r] * inv);
    }
  }
}

// ------------------------------ add + LayerNorm ----------------------------
__global__ __launch_bounds__(256) void k_add_ln(const float* __restrict__ xa,
                                                const u16* __restrict__ xb,
                                                const float* __restrict__ g,
                                                const float* __restrict__ be,
                                                float* __restrict__ of, u16* __restrict__ ob) {
  const int wave = threadIdx.x >> 6, lane = threadIdx.x & 63;
  const int row = blockIdx.x * 4 + wave;
  const float4 a = ((const float4*)(xa + (size_t)row * kD))[lane];
  uint2 bw = ((const uint2*)(xb + (size_t)row * kD))[lane];
  float b0, b1, b2, b3;
  unpack2(bw.x, b0, b1);
  unpack2(bw.y, b2, b3);
  float x0 = a.x + b0, x1 = a.y + b1, x2 = a.z + b2, x3 = a.w + b3;
  float sum = x0 + x1 + x2 + x3;
  float sq = fmaf(x0, x0, fmaf(x1, x1, fmaf(x2, x2, x3 * x3)));
  for (int off = 1; off < 64; off <<= 1) {
    sum += __shfl_xor(sum, off);
    sq += __shfl_xor(sq, off);
  }
  const float mean = sum * (1.f / 256.f);
  const float var = sq * (1.f / 256.f) - mean * mean;
  const float rs = rsqrtf(var + kEps);
  const float4 gg = ((const float4*)g)[lane];
  const float4 bt = ((const float4*)be)[lane];
  float y0 = (x0 - mean) * rs * gg.x + bt.x;
  float y1 = (x1 - mean) * rs * gg.y + bt.y;
  float y2 = (x2 - mean) * rs * gg.z + bt.z;
  float y3 = (x3 - mean) * rs * gg.w + bt.w;
  float4 yo = {y0, y1, y2, y3};
  ((float4*)(of + (size_t)row * kD))[lane] = yo;
  if (ob) {
    u16* po = ob + (size_t)row * kD + lane * 4;
    po[0] = f2b(y0); po[1] = f2b(y1); po[2] = f2b(y2); po[3] = f2b(y3);
  }
}

// add+LN over state + three bf16 conv partials (LN1).
__global__ __launch_bounds__(256) void k_add_ln3(const float* __restrict__ xa,
                                                 const u16* __restrict__ pa,
                                                 const u16* __restrict__ pbq,
                                                 const u16* __restrict__ pc,
                                                 const float* __restrict__ g,
                                                 const float* __restrict__ be,
                                                 float* __restrict__ of, u16* __restrict__ ob) {
  const int wave = threadIdx.x >> 6, lane = threadIdx.x & 63;
  const int row = blockIdx.x * 4 + wave;
  const size_t base = (size_t)row * kD;
  const float4 a = ((const float4*)(xa + base))[lane];
  uint2 w0 = ((const uint2*)(pa + base))[lane];
  uint2 w1 = ((const uint2*)(pbq + base))[lane];
  uint2 w2 = ((const uint2*)(pc + base))[lane];
  float a0, a1, a2, a3, c0, c1, c2, c3, d0, d1, d2, d3;
  unpack2(w0.x, a0, a1); unpack2(w0.y, a2, a3);
  unpack2(w1.x, c0, c1); unpack2(w1.y, c2, c3);
  unpack2(w2.x, d0, d1); unpack2(w2.y, d2, d3);
  float x0 = a.x + a0 + c0 + d0, x1 = a.y + a1 + c1 + d1;
  float x2 = a.z + a2 + c2 + d2, x3 = a.w + a3 + c3 + d3;
  float sum = x0 + x1 + x2 + x3;
  float sq = fmaf(x0, x0, fmaf(x1, x1, fmaf(x2, x2, x3 * x3)));
  for (int off = 1; off < 64; off <<= 1) {
    sum += __shfl_xor(sum, off);
    sq += __shfl_xor(sq, off);
  }
  const float mean = sum * (1.f / 256.f);
  const float var = sq * (1.f / 256.f) - mean * mean;
  const float rs = rsqrtf(var + kEps);
  const float4 gg = ((const float4*)g)[lane];
  const float4 bt = ((const float4*)be)[lane];
  float y0 = (x0 - mean) * rs * gg.x + bt.x;
  float y1 = (x1 - mean) * rs * gg.y + bt.y;
  float y2 = (x2 - mean) * rs * gg.z + bt.z;
  float y3 = (x3 - mean) * rs * gg.w + bt.w;
  float4 yo = {y0, y1, y2, y3};
  ((float4*)(of + base))[lane] = yo;
  u16* po = ob + base + lane * 4;
  po[0] = f2b(y0); po[1] = f2b(y1); po[2] = f2b(y2); po[3] = f2b(y3);
}

// ------------------------------ launch -------------------------------------
extern "C" void kernel_launch(void* const* d_in, const int* in_sizes, int n_in,
                              void* d_out, int out_size, void* d_ws, size_t ws_size,
                              hipStream_t stream) {
  const float* state = (const float*)d_in[0];
  const float* conv_w = (const float*)d_in[1];
  const float* conv_b = (const float*)d_in[2];
  const float* qkv_w = (const float*)d_in[3];
  const float* qkv_b = (const float*)d_in[4];
  const float* o_w = (const float*)d_in[5];
  const float* o_b = (const float*)d_in[6];
  const float* attn_bias = (const float*)d_in[7];
  const float* ffp_w = (const float*)d_in[8];
  const float* ffp_b = (const float*)d_in[9];
  const float* ffg_w = (const float*)d_in[10];
  const float* ffg_b = (const float*)d_in[11];
  const float* ffo_w = (const float*)d_in[12];
  const float* ffo_b = (const float*)d_in[13];
  const float* n1_g = (const float*)d_in[14];
  const float* n1_b = (const float*)d_in[15];
  const float* n2_g = (const float*)d_in[16];
  const float* n2_b = (const float*)d_in[17];
  const float* n3_g = (const float*)d_in[18];
  const float* n3_b = (const float*)d_in[19];

  // ---- workspace layout: 137,527,296 bytes, phase-overlapped ----
  constexpr size_t kWsNeed = 137527296;
  if (ws_size < kWsNeed) {
    fprintf(stderr, "[kernel] ws_size=%zu < need=%zu\n", ws_size, kWsNeed);
    return;
  }
  char* ws = (char*)d_ws;
  u16* Wc = (u16*)(ws + 0);             // [27][256][256] bf16  (3,538,944 B)
  u16* Wqkv = (u16*)(ws + 3538944);     // [768][256]
  u16* Wo = (u16*)(ws + 3932160);       // [256][256]
  u16* Wff = (u16*)(ws + 4063232);      // [2048][256] (proj;gate)
  u16* Wffo = (u16*)(ws + 5111808);     // [256][1024]  (ends 5,636,096)
  float* stF = (float*)(ws + 5636096);  // [36800][256] f32 state (37,683,200 B)
  u16* stB = (u16*)(ws + 43319296);     // [36800][256] bf16 (18,841,600 B)
  char* S4 = ws + 62160896;             // 75,366,400 B shared slot
  // conv phase overlays:
  u16* X0 = (u16*)(ws + 5636096);       // in stF slot: [64][576][256] bf16
  u16* zrow = (u16*)(ws + 43319296);    // in stB slot: 256 zeros
  u16* pd = (u16*)S4;                   // 3 partials, stride kPdStride u16
  // attn/ffn phase overlays:
  u16* qkvb = (u16*)S4;                 // [36800][768] bf16 (56.5 MB)
  u16* attnout = (u16*)(S4 + 56524800); // [36800][256] bf16
  u16* oprojb = (u16*)S4;               // [36800][256] bf16
  u16* ffh = (u16*)S4;                  // [36800][1024] bf16 (75.4 MB)
  float* outp = (float*)d_out;

  // ---- pack weights / inputs to bf16 (every call; no cached state) ----
  k_pack_convw<<<768, 256, 0, stream>>>(conv_w, Wc);
  k_tobf16<<<768, 256, 0, stream>>>(qkv_w, Wqkv, 768 * 256);
  k_tobf16<<<256, 256, 0, stream>>>(o_w, Wo, 256 * 256);
  k_tobf16<<<1024, 256, 0, stream>>>(ffp_w, Wff, 1024 * 256);
  k_tobf16<<<1024, 256, 0, stream>>>(ffg_w, Wff + 1024 * 256, 1024 * 256);
  k_tobf16<<<1024, 256, 0, stream>>>(ffo_w, Wffo, 256 * 1024);
  k_make_x0<<<kB * kP + 1, 256, 0, stream>>>(state, X0, zrow);

  // ---- conv (3 dilation partials) + LN1 ----
  k_conv<<<dim3(288, 2, 3), 256, 0, stream>>>(X0, zrow, Wc, conv_b, pd);
  k_add_ln3<<<kRows / 4, 256, 0, stream>>>(state, pd, pd + kPdStride, pd + 2 * kPdStride,
                                           n1_g, n1_b, stF, stB);

  // ---- attention ----
  k_gemm<<<dim3(288, 6), 256, 0, stream>>>(stB, Wqkv, qkv_b, qkvb, kRows, 768, 256);
  k_attn2<<<dim3(9, kH, kB), 256, 0, stream>>>(qkvb, attn_bias, attnout);
  k_gemm<<<dim3(288, 2), 256, 0, stream>>>(attnout, Wo, o_b, oprojb, kRows, 256, 256);
  k_add_ln<<<kRows / 4, 256, 0, stream>>>(stF, oprojb, n2_g, n2_b, stF, stB);

  // ---- FFN ----
  k_ff1<<<dim3(288, 8), 256, 0, stream>>>(stB, Wff, ffp_b, ffg_b, ffh, kRows);
  k_gemm<<<dim3(288, 2), 256, 0, stream>>>(ffh, Wffo, ffo_b, stB, kRows, 256, 1024);
  k_add_ln<<<kRows / 4, 256, 0, stream>>>(stF, stB, n3_g, n3_b, outp, nullptr);
}

// Round 16
// 513.571 us; speedup vs baseline: 1.3451x; 1.0046x over previous
//
#include <hip/hip_runtime.h>
#include <hip/hip_bf16.h>
#include <cstdio>

// ---------------------------------------------------------------------------
// SyndromeTransformerLayer on MI355X.  Round 16: R15 best-known (515.9 us) +
// merged weight-pack kernel (5 k_tobf16 launches -> 1 k_pack_wall).
// conv: R9 depth-2 counted-vmcnt pipeline (155 us, MfmaUtil 37%).
// k_gemm / k_ff1: R8 dbuf stage-early + single __syncthreads.
// k_attn2: R9 synchronous staging.  LN kernels unchanged.
// Workspace: 137,527,296 B, phase-overlapped slots.
// ---------------------------------------------------------------------------

typedef __attribute__((ext_vector_type(8))) short s8v;    // 8 bf16 (4 VGPRs)
typedef __attribute__((ext_vector_type(4))) float f32x4;  // MFMA accumulator
typedef unsigned short u16;

constexpr int kB = 64, kS = 575, kD = 256, kH = 8, kP = 576, kFF = 1024;
constexpr int kRows = kB * kS;  // 36800
constexpr float kEps = 1e-5f;
constexpr float kScale = 0.17677669529663687f;  // 1/sqrt(32)
constexpr size_t kPdStride = 9420800;  // u16 elements per conv partial

__device__ __forceinline__ u16 f2b(float f) {
  __hip_bfloat16 h = __float2bfloat16(f);
  return *reinterpret_cast<u16*>(&h);
}
__device__ __forceinline__ void unpack2(unsigned int w, float& lo, float& hi) {
  union { float f; unsigned int u; } a, b;
  a.u = w << 16;
  b.u = w & 0xffff0000u;
  lo = a.f;
  hi = b.f;
}

__device__ __forceinline__ void gll16(const void* g, void* l) {
  __builtin_amdgcn_global_load_lds((const __attribute__((address_space(1))) void*)g,
                                   (__attribute__((address_space(3))) void*)l, 16, 0, 0);
}

// ------------------------------ packing ------------------------------------
// One block per (i,co) pair: reads 2304 contiguous floats (thread ci takes its
// 9), writes wc[tap][co][ci].
__global__ void k_pack_convw(const float* __restrict__ cw, u16* __restrict__ wc) {
  const int blk = blockIdx.x;   // i*256 + co
  const int ci = threadIdx.x;
  const int i = blk >> 8, co = blk & 255;
  const float* src = cw + (size_t)blk * 2304 + ci * 9;
  float v[9];
#pragma unroll
  for (int r = 0; r < 9; ++r) v[r] = src[r];
#pragma unroll
  for (int r = 0; r < 9; ++r)
    wc[(((size_t)(i * 9 + r)) << 16) + (co << 8) + ci] = f2b(v[r]);
}

// All five dense-weight bf16 packs in ONE launch.  Flat quad index over
// 1,048,576 f32 elements; ranges (in float4 quads):
//   [0,49152)        qkv_w  -> Wqkv
//   [49152,65536)    o_w    -> Wo
//   [65536,131072)   ffp_w  -> Wff
//   [131072,196608)  ffg_w  -> Wff + 262144
//   [196608,262144)  ffo_w  -> Wffo
__global__ void k_pack_wall(const float* __restrict__ qkv_w,
                            const float* __restrict__ o_w,
                            const float* __restrict__ ffp_w,
                            const float* __restrict__ ffg_w,
                            const float* __restrict__ ffo_w,
                            u16* __restrict__ Wqkv, u16* __restrict__ Wo,
                            u16* __restrict__ Wff, u16* __restrict__ Wffo) {
  const int q = blockIdx.x * 256 + threadIdx.x;  // 0..262143
  const float* src;
  u16* dst;
  int off;
  if (q < 49152) {
    src = qkv_w; dst = Wqkv; off = q;
  } else if (q < 65536) {
    src = o_w; dst = Wo; off = q - 49152;
  } else if (q < 131072) {
    src = ffp_w; dst = Wff; off = q - 65536;
  } else if (q < 196608) {
    src = ffg_w; dst = Wff + 262144; off = q - 131072;
  } else {
    src = ffo_w; dst = Wffo; off = q - 196608;
  }
  const float4 v = ((const float4*)src)[off];
  ushort4 o4;
  o4.x = f2b(v.x); o4.y = f2b(v.y); o4.z = f2b(v.z); o4.w = f2b(v.w);
  ((ushort4*)dst)[off] = o4;
}

// X0[b][p][c]: p=0 is the zero pad row, else state[b][p-1][c], bf16.
// Extra block (bp == kB*kP) writes the 256-element zero row used by k_conv.
__global__ void k_make_x0(const float* __restrict__ state, u16* __restrict__ x0,
                          u16* __restrict__ zrow) {
  int bp = blockIdx.x;  // b*576 + p, or kB*kP for the zero row
  int c = threadIdx.x;
  if (bp == kB * kP) { zrow[c] = 0; return; }
  int p = bp % kP;
  int b = bp / kP;
  float v = (p == 0) ? 0.f : state[((size_t)(b * kS + p - 1)) * kD + c];
  x0[(size_t)bp * kD + c] = f2b(v);
}

// ------------------------------ GEMM (BK=64, dbuf stage-early) -------------
// C[M][N] = A[M][K](bf16) @ Bw[N][K]^T(bf16) + bias[N], bf16 out.
// 128x128 tile, BK=64, double-buffered LDS, stage-early + 1 sync/step.
// Chunk-XOR swizzle: source chunk (lane&7)^(lane>>3); ds_read XORs back.
// N mult of 128, K mult of 64; M guarded.
__global__ __launch_bounds__(256) void k_gemm(const u16* __restrict__ A,
                                              const u16* __restrict__ Bw,
                                              const float* __restrict__ bias,
                                              u16* __restrict__ Cb,
                                              int M, int N, int K) {
  __shared__ u16 As[2][8192];  // [128][64] x2
  __shared__ u16 Bs[2][8192];
  const int t = threadIdx.x;
  const int wave = t >> 6, lane = t & 63;
  const int wm = wave >> 1, wn = wave & 1;
  const int lr = lane & 15, lk = lane >> 4;
  const int m0 = blockIdx.x * 128, n0 = blockIdx.y * 128;
  const int lrow = lane >> 3;                // 0..7
  const int swzk = ((lane & 7) ^ lrow) * 8;  // swizzled source chunk (u16)
  const u16 *ga[4], *gb[4];
#pragma unroll
  for (int i = 0; i < 4; ++i) {
    int r = 8 * wave + lrow + 32 * i;
    int ra = m0 + r;
    if (ra > M - 1) ra = M - 1;  // clamp: garbage rows are never stored
    ga[i] = A + (size_t)ra * K + swzk;
    gb[i] = Bw + (size_t)(n0 + r) * K + swzk;
  }
  auto stage = [&](int kt, int buf) {
#pragma unroll
    for (int i = 0; i < 4; ++i) {
      gll16(ga[i] + kt, &As[buf][i * 2048 + wave * 512]);
      gll16(gb[i] + kt, &Bs[buf][i * 2048 + wave * 512]);
    }
  };
  f32x4 acc[4][4] = {};
  stage(0, 0);
  __syncthreads();
  const int NT = K >> 6;
  for (int s = 0; s < NT; ++s) {
    const int cur = s & 1;
    if (s + 1 < NT) stage((s + 1) << 6, cur ^ 1);  // prefetch overlaps MFMA
    s8v af[2][4], bfr[2][4];
#pragma unroll
    for (int kk = 0; kk < 2; ++kk)
#pragma unroll
      for (int i = 0; i < 4; ++i) {
        const int rA = wm * 64 + i * 16 + lr;
        const int rB = wn * 64 + i * 16 + lr;
        af[kk][i] = *(const s8v*)(&As[cur][rA * 64 + ((kk * 32 + lk * 8) ^ ((rA & 7) << 3))]);
        bfr[kk][i] = *(const s8v*)(&Bs[cur][rB * 64 + ((kk * 32 + lk * 8) ^ ((rB & 7) << 3))]);
      }
#pragma unroll
    for (int kk = 0; kk < 2; ++kk)
#pragma unroll
      for (int i = 0; i < 4; ++i)
#pragma unroll
        for (int j = 0; j < 4; ++j)
          acc[i][j] = __builtin_amdgcn_mfma_f32_16x16x32_bf16(af[kk][i], bfr[kk][j], acc[i][j], 0, 0, 0);
    __syncthreads();  // drains prefetch + orders reads before next overwrite
  }
#pragma unroll
  for (int i = 0; i < 4; ++i) {
    const int rbase = m0 + wm * 64 + i * 16 + lk * 4;
#pragma unroll
    for (int j = 0; j < 4; ++j) {
      const int col = n0 + wn * 64 + j * 16 + lr;
      const float bv = bias[col];
#pragma unroll
      for (int q = 0; q < 4; ++q) {
        int r = rbase + q;
        if (r < M) Cb[(size_t)r * N + col] = f2b(acc[i][j][q] + bv);
      }
    }
  }
}

// ------------------------------ FF1 + fused sigmoid gate -------------------
// H[r][c] = (A@Wff[c]^T + pb[c]) * sigmoid(A@Wff[1024+c]^T + gb[c]).
// BK=32, double-buffered (48 KB), stage-early + 1 sync/step, chunk-XOR
// swizzle (4 chunks/row): source chunk (t&3)^((t>>2)&3), read XOR (row&3)<<3.
__global__ __launch_bounds__(256) void k_ff1(const u16* __restrict__ A,
                                             const u16* __restrict__ Wf,
                                             const float* __restrict__ pb,
                                             const float* __restrict__ gb,
                                             u16* __restrict__ H, int M) {
  __shared__ u16 As[2][4096];
  __shared__ u16 Bp[2][4096];
  __shared__ u16 Bg[2][4096];
  const int t = threadIdx.x;
  const int wave = t >> 6;
  const int wm = wave >> 1, wn = wave & 1;
  const int lr = t & 15, lk = (t & 63) >> 4;
  const int m0 = blockIdx.x * 128, n0 = blockIdx.y * 128;
  int ra = m0 + (t >> 2);
  int rb = ra + 64;
  if (ra > M - 1) ra = M - 1;
  if (rb > M - 1) rb = M - 1;
  const int koff = (((t & 3) ^ ((t >> 2) & 3)) * 8);  // swizzled source chunk
  const u16* gA0 = A + (size_t)ra * kD + koff;
  const u16* gA1 = A + (size_t)rb * kD + koff;
  const u16* gP0 = Wf + (size_t)(n0 + (t >> 2)) * kD + koff;
  const u16* gP1 = gP0 + (size_t)64 * kD;
  const u16* gG0 = gP0 + (size_t)1024 * kD;
  const u16* gG1 = gP1 + (size_t)1024 * kD;
  auto stage = [&](int kt, int buf) {
    gll16(gA0 + kt, &As[buf][wave * 512]);
    gll16(gA1 + kt, &As[buf][2048 + wave * 512]);
    gll16(gP0 + kt, &Bp[buf][wave * 512]);
    gll16(gP1 + kt, &Bp[buf][2048 + wave * 512]);
    gll16(gG0 + kt, &Bg[buf][wave * 512]);
    gll16(gG1 + kt, &Bg[buf][2048 + wave * 512]);
  };
  f32x4 ap[4][4] = {};
  f32x4 ag[4][4] = {};
  stage(0, 0);
  __syncthreads();
  for (int s = 0; s < 8; ++s) {
    const int cur = s & 1;
    if (s < 7) stage((s + 1) << 5, cur ^ 1);
    s8v af[4], bp4[4], bg4[4];
#pragma unroll
    for (int i = 0; i < 4; ++i) {
      const int rA = wm * 64 + i * 16 + lr;
      const int rB = wn * 64 + i * 16 + lr;
      const int oA = rA * 32 + ((lk * 8) ^ ((rA & 3) << 3));
      const int oB = rB * 32 + ((lk * 8) ^ ((rB & 3) << 3));
      af[i] = *(const s8v*)(&As[cur][oA]);
      bp4[i] = *(const s8v*)(&Bp[cur][oB]);
      bg4[i] = *(const s8v*)(&Bg[cur][oB]);
    }
#pragma unroll
    for (int i = 0; i < 4; ++i)
#pragma unroll
      for (int j = 0; j < 4; ++j) {
        ap[i][j] = __builtin_amdgcn_mfma_f32_16x16x32_bf16(af[i], bp4[j], ap[i][j], 0, 0, 0);
        ag[i][j] = __builtin_amdgcn_mfma_f32_16x16x32_bf16(af[i], bg4[j], ag[i][j], 0, 0, 0);
      }
    __syncthreads();
  }
#pragma unroll
  for (int i = 0; i < 4; ++i) {
    const int rbase = m0 + wm * 64 + i * 16 + lk * 4;
#pragma unroll
    for (int j = 0; j < 4; ++j) {
      const int col = n0 + wn * 64 + j * 16 + lr;
      const float pbv = pb[col], gbv = gb[col];
#pragma unroll
      for (int q = 0; q < 4; ++q) {
        int r = rbase + q;
        if (r < M) {
          float p = ap[i][j][q] + pbv;
          float g = ag[i][j][q] + gbv;
          H[(size_t)r * kFF + col] = f2b(p * (1.f / (1.f + __expf(-g))));
        }
      }
    }
  }
}

// ------------------------------ conv (counted-vmcnt pipeline, R9) ----------
__global__ __launch_bounds__(256) void k_conv(const u16* __restrict__ X0,
                                              const u16* __restrict__ zrow,
                                              const u16* __restrict__ Wc,
                                              const float* __restrict__ cb,
                                              u16* __restrict__ pd) {
  __shared__ u16 As[2][8192];  // [128][64] x2
  __shared__ u16 Bs[2][8192];
  const int t = threadIdx.x;
  const int wave = t >> 6, lane = t & 63;
  const int wm = wave >> 1, wn = wave & 1;
  const int lr = lane & 15, lk = lane >> 4;
  const int m0 = blockIdx.x * 128;
  const int n0 = blockIdx.y * 128;
  const int di = blockIdx.z;
  const int dil = 1 << di;
  const int lrow = lane >> 3;
  const int swzk = ((lane & 7) ^ lrow) * 8;
  const u16* Wd = Wc + ((size_t)di * 9 << 16);
  int py[4], px[4];
  const u16* xrow[4];
  const u16* gw[4];
#pragma unroll
  for (int i = 0; i < 4; ++i) {
    int r = 8 * wave + lrow + 32 * i;
    int m = m0 + r;                 // 0..36863
    int bbv = m / 576;
    int p = m - bbv * 576;
    py[i] = p / 24;
    px[i] = p - py[i] * 24;
    xrow[i] = X0 + (((size_t)(bbv * kP)) << 8) + swzk;
    gw[i] = Wd + (size_t)(n0 + r) * kD + swzk;
  }
  const u16* S0[4];
  const u16* S1[4];
  auto csrc = [&](const u16** dst, int dyv, int dxv) {
#pragma unroll
    for (int i = 0; i < 4; ++i) {
      const int ny = py[i] + dyv, nx = px[i] + dxv;
      const bool v = ((unsigned)ny < 24u) & ((unsigned)nx < 24u);
      dst[i] = v ? xrow[i] + ((ny * 24 + nx) << 8) : zrow + swzk;
    }
  };
  auto stage = [&](const u16* const* S, size_t woff, int kc, int buf) {
#pragma unroll
    for (int i = 0; i < 4; ++i) {
      gll16(S[i] + kc, &As[buf][i * 2048 + wave * 512]);
      gll16(gw[i] + woff + kc, &Bs[buf][i * 2048 + wave * 512]);
    }
  };
  f32x4 acc[4][4] = {};
  csrc(S0, -dil, -dil);   // tap 0
  stage(S0, 0, 0, 0);     // step 0 -> buf 0
  stage(S0, 0, 64, 1);    // step 1 -> buf 1
  for (int tap = 0; tap < 9; ++tap) {
    if (tap < 8) {
      const int tn = tap + 1;
      csrc(S1, (tn / 3 - 1) * dil, (tn % 3 - 1) * dil);
    }
    const size_t woff = (size_t)tap << 16;
#pragma unroll
    for (int c = 0; c < 4; ++c) {
      const int buf = c & 1;  // step s = tap*4+c; s&1 == c&1
      if (c == 3 && tap == 8) {
        asm volatile("s_waitcnt vmcnt(0)" ::: "memory");
      } else {
        asm volatile("s_waitcnt vmcnt(8)" ::: "memory");
      }
      __builtin_amdgcn_s_barrier();
      s8v af[2][4], bfr[2][4];
#pragma unroll
      for (int kk = 0; kk < 2; ++kk)
#pragma unroll
        for (int ii = 0; ii < 4; ++ii) {
          const int rA = wm * 64 + ii * 16 + lr;
          const int rB = wn * 64 + ii * 16 + lr;
          af[kk][ii] = *(const s8v*)(&As[buf][rA * 64 + ((kk * 32 + lk * 8) ^ ((rA & 7) << 3))]);
          bfr[kk][ii] = *(const s8v*)(&Bs[buf][rB * 64 + ((kk * 32 + lk * 8) ^ ((rB & 7) << 3))]);
        }
#pragma unroll
      for (int kk = 0; kk < 2; ++kk)
#pragma unroll
        for (int ii = 0; ii < 4; ++ii)
#pragma unroll
          for (int jj = 0; jj < 4; ++jj)
            acc[ii][jj] = __builtin_amdgcn_mfma_f32_16x16x32_bf16(af[kk][ii], bfr[kk][jj], acc[ii][jj], 0, 0, 0);
      __builtin_amdgcn_s_barrier();
      if (c == 0) {
        stage(S0, woff, 128, buf);
      } else if (c == 1) {
        stage(S0, woff, 192, buf);
      } else if (c == 2) {
        if (tap < 8) stage(S1, woff + 65536, 0, buf);
      } else {
        if (tap < 8) stage(S1, woff + 65536, 64, buf);
      }
    }
#pragma unroll
    for (int i = 0; i < 4; ++i) S0[i] = S1[i];
  }
  u16* pdo = pd + (size_t)di * kPdStride;
#pragma unroll
  for (int i2 = 0; i2 < 4; ++i2) {
    const int mbase = m0 + wm * 64 + i2 * 16 + lk * 4;
#pragma unroll
    for (int j = 0; j < 4; ++j) {
      const int col = n0 + wn * 64 + j * 16 + lr;
      const float bv = cb[di * kD + col];
#pragma unroll
      for (int q = 0; q < 4; ++q) {
        const int m = mbase + q;
        const int b2 = m / 576;
        const int p = m - b2 * 576;
        if (p >= 1)
          pdo[((size_t)(b2 * kS + p - 1) << 8) + col] = f2b(acc[i2][j][q] + bv);
      }
    }
  }
}

// ------------------------------ attention (MFMA flash, R9 version) ---------
// Reference reshape quirk: q.reshape(b,h,s,hd) on (b,s,256) means head h, pos s'
// = contiguous 32 elems at flat offset h*575*32 + s'*32 of the q block.
// Block: 4 waves, 64 q-rows; K-loop over 575 keys in 9 tiles of 64 (masked).
__global__ __launch_bounds__(256) void k_attn2(const u16* __restrict__ qkv,
                                               const float* __restrict__ bias,
                                               u16* __restrict__ outp) {
  __shared__ u16 KsS[2][2048];  // [64 keys][32 d], swizzled
  __shared__ u16 VtS[2][2048];  // [32 d][64 keys], swizzled
  __shared__ u16 PsS[4][1024];  // per-wave [16 q][64 keys], swizzled
  const int qt = blockIdx.x, h = blockIdx.y, b = blockIdx.z;
  const int tid = threadIdx.x;
  const int w = tid >> 6, lane = tid & 63;
  const int lg = lane >> 4, lr = lane & 15;
  const int q0 = qt * 64;
  const int qrow_a = q0 + w * 16 + lr;
  const int qrow_ac = qrow_a < kS ? qrow_a : kS - 1;
  s8v qf;
  {
    int F = h * (kS * 32) + qrow_ac * 32 + lg * 8;
    qf = *(const s8v*)(qkv + ((size_t)(b * kS + (F >> 8))) * 768 + (F & 255));
  }
  const int trel = tid >> 2;
  const int dcol = (tid & 3) * 8;
  float mrun[4], lsum[4];
#pragma unroll
  for (int r = 0; r < 4; ++r) { mrun[r] = -1e30f; lsum[r] = 0.f; }
  f32x4 o0 = {0.f, 0.f, 0.f, 0.f}, o1 = {0.f, 0.f, 0.f, 0.f};
  const f32x4 zf = {0.f, 0.f, 0.f, 0.f};
  const int qrow_s = q0 + w * 16 + lg * 4;  // +r
  const size_t kvrowbase = (size_t)(b * kS) * 768;

  for (int kt = 0; kt < 9; ++kt) {
    const int t0 = kt * 64;
    const int buf = kt & 1;
    {
      const int tg = t0 + trel;
      const bool tv = tg < kS;
      const int tcl = tv ? tg : kS - 1;
      const int Fk = h * (kS * 32) + tcl * 32 + dcol;
      const u16* kp = qkv + kvrowbase + (size_t)(Fk >> 8) * 768 + 256 + (Fk & 255);
      uint4 kd = {0, 0, 0, 0}, vd = {0, 0, 0, 0};
      if (tv) {
        kd = *(const uint4*)kp;
        vd = *(const uint4*)(kp + 256);
      }
      *(uint4*)&KsS[buf][trel * 32 + (dcol ^ ((trel & 3) << 3))] = kd;
      union { uint4 u4; u16 us[8]; } vu;
      vu.u4 = vd;
#pragma unroll
      for (int j = 0; j < 8; ++j) {
        const int d = dcol + j;
        VtS[buf][d * 64 + (trel ^ ((d & 7) << 3))] = vu.us[j];
      }
    }
    float bv[4][4];  // [j key-subtile][r q-row]
#pragma unroll
    for (int r = 0; r < 4; ++r) {
      const int qr = qrow_s + r;
      const float* bp = bias + ((size_t)h * kS + (qr < kS ? qr : kS - 1)) * kS;
#pragma unroll
      for (int j = 0; j < 4; ++j) {
        const int tg = t0 + j * 16 + lr;
        bv[j][r] = (tg < kS) ? bp[tg] : -1e30f;
      }
    }
    __syncthreads();
    f32x4 sc[4];
#pragma unroll
    for (int j = 0; j < 4; ++j) {
      const int krow = j * 16 + lr;
      s8v kf = *(const s8v*)&KsS[buf][krow * 32 + ((lg * 8) ^ ((krow & 3) << 3))];
      sc[j] = __builtin_amdgcn_mfma_f32_16x16x32_bf16(qf, kf, zf, 0, 0, 0);
    }
#pragma unroll
    for (int r = 0; r < 4; ++r) {
      float s4[4];
      float sm = -1e30f;
#pragma unroll
      for (int j = 0; j < 4; ++j) {
        s4[j] = fmaf(sc[j][r], kScale, bv[j][r]);
        sm = fmaxf(sm, s4[j]);
      }
      sm = fmaxf(sm, __shfl_xor(sm, 1));
      sm = fmaxf(sm, __shfl_xor(sm, 2));
      sm = fmaxf(sm, __shfl_xor(sm, 4));
      sm = fmaxf(sm, __shfl_xor(sm, 8));
      const float nm = fmaxf(mrun[r], sm);
      const float corr = __expf(mrun[r] - nm);
      mrun[r] = nm;
      float psum = 0.f;
      const int prow = lg * 4 + r;
#pragma unroll
      for (int j = 0; j < 4; ++j) {
        const float p = __expf(s4[j] - nm);
        psum += p;
        PsS[w][prow * 64 + ((j * 16 + lr) ^ ((prow & 7) << 3))] = f2b(p);
      }
      lsum[r] = fmaf(lsum[r], corr, psum);
      o0[r] *= corr;
      o1[r] *= corr;
    }
#pragma unroll
    for (int c = 0; c < 2; ++c) {
      const int pcol = c * 32 + lg * 8;
      s8v pf = *(const s8v*)&PsS[w][lr * 64 + (pcol ^ ((lr & 7) << 3))];
      s8v vf0 = *(const s8v*)&VtS[buf][lr * 64 + (pcol ^ ((lr & 7) << 3))];
      s8v vf1 = *(const s8v*)&VtS[buf][(16 + lr) * 64 + (pcol ^ (((16 + lr) & 7) << 3))];
      o0 = __builtin_amdgcn_mfma_f32_16x16x32_bf16(pf, vf0, o0, 0, 0, 0);
      o1 = __builtin_amdgcn_mfma_f32_16x16x32_bf16(pf, vf1, o1, 0, 0, 0);
    }
  }
#pragma unroll
  for (int r = 0; r < 4; ++r) {
    float lt = lsum[r];
    lt += __shfl_xor(lt, 1);
    lt += __shfl_xor(lt, 2);
    lt += __shfl_xor(lt, 4);
    lt += __shfl_xor(lt, 8);
    const float inv = 1.f / lt;
    const int qr = qrow_s + r;
    if (qr < kS) {
      u16* op = outp + ((size_t)(b * kS + qr)) * kD + h * 32;
      op[lr] = f2b(o0[r] * inv);
      op[16 + lr] = f2b(o1[r] * inv);
    }
  }
}

// ------------------------------ add + LayerNorm ----------------------------
__global__ __launch_bounds__(256) void k_add_ln(const float* __restrict__ xa,
                                                const u16* __restrict__ xb,
                                                const float* __restrict__ g,
                                                const float* __restrict__ be,
                                                float* __restrict__ of, u16* __restrict__ ob) {
  const int wave = threadIdx.x >> 6, lane = threadIdx.x & 63;
  const int row = blockIdx.x * 4 + wave;
  const float4 a = ((const float4*)(xa + (size_t)row * kD))[lane];
  uint2 bw = ((const uint2*)(xb + (size_t)row * kD))[lane];
  float b0, b1, b2, b3;
  unpack2(bw.x, b0, b1);
  unpack2(bw.y, b2, b3);
  float x0 = a.x + b0, x1 = a.y + b1, x2 = a.z + b2, x3 = a.w + b3;
  float sum = x0 + x1 + x2 + x3;
  float sq = fmaf(x0, x0, fmaf(x1, x1, fmaf(x2, x2, x3 * x3)));
  for (int off = 1; off < 64; off <<= 1) {
    sum += __shfl_xor(sum, off);
    sq += __shfl_xor(sq, off);
  }
  const float mean = sum * (1.f / 256.f);
  const float var = sq * (1.f / 256.f) - mean * mean;
  const float rs = rsqrtf(var + kEps);
  const float4 gg = ((const float4*)g)[lane];
  const float4 bt = ((const float4*)be)[lane];
  float y0 = (x0 - mean) * rs * gg.x + bt.x;
  float y1 = (x1 - mean) * rs * gg.y + bt.y;
  float y2 = (x2 - mean) * rs * gg.z + bt.z;
  float y3 = (x3 - mean) * rs * gg.w + bt.w;
  float4 yo = {y0, y1, y2, y3};
  ((float4*)(of + (size_t)row * kD))[lane] = yo;
  if (ob) {
    u16* po = ob + (size_t)row * kD + lane * 4;
    po[0] = f2b(y0); po[1] = f2b(y1); po[2] = f2b(y2); po[3] = f2b(y3);
  }
}

// add+LN over state + three bf16 conv partials (LN1).
__global__ __launch_bounds__(256) void k_add_ln3(const float* __restrict__ xa,
                                                 const u16* __restrict__ pa,
                                                 const u16* __restrict__ pbq,
                                                 const u16* __restrict__ pc,
                                                 const float* __restrict__ g,
                                                 const float* __restrict__ be,
                                                 float* __restrict__ of, u16* __restrict__ ob) {
  const int wave = threadIdx.x >> 6, lane = threadIdx.x & 63;
  const int row = blockIdx.x * 4 + wave;
  const size_t base = (size_t)row * kD;
  const float4 a = ((const float4*)(xa + base))[lane];
  uint2 w0 = ((const uint2*)(pa + base))[lane];
  uint2 w1 = ((const uint2*)(pbq + base))[lane];
  uint2 w2 = ((const uint2*)(pc + base))[lane];
  float a0, a1, a2, a3, c0, c1, c2, c3, d0, d1, d2, d3;
  unpack2(w0.x, a0, a1); unpack2(w0.y, a2, a3);
  unpack2(w1.x, c0, c1); unpack2(w1.y, c2, c3);
  unpack2(w2.x, d0, d1); unpack2(w2.y, d2, d3);
  float x0 = a.x + a0 + c0 + d0, x1 = a.y + a1 + c1 + d1;
  float x2 = a.z + a2 + c2 + d2, x3 = a.w + a3 + c3 + d3;
  float sum = x0 + x1 + x2 + x3;
  float sq = fmaf(x0, x0, fmaf(x1, x1, fmaf(x2, x2, x3 * x3)));
  for (int off = 1; off < 64; off <<= 1) {
    sum += __shfl_xor(sum, off);
    sq += __shfl_xor(sq, off);
  }
  const float mean = sum * (1.f / 256.f);
  const float var = sq * (1.f / 256.f) - mean * mean;
  const float rs = rsqrtf(var + kEps);
  const float4 gg = ((const float4*)g)[lane];
  const float4 bt = ((const float4*)be)[lane];
  float y0 = (x0 - mean) * rs * gg.x + bt.x;
  float y1 = (x1 - mean) * rs * gg.y + bt.y;
  float y2 = (x2 - mean) * rs * gg.z + bt.z;
  float y3 = (x3 - mean) * rs * gg.w + bt.w;
  float4 yo = {y0, y1, y2, y3};
  ((float4*)(of + base))[lane] = yo;
  u16* po = ob + base + lane * 4;
  po[0] = f2b(y0); po[1] = f2b(y1); po[2] = f2b(y2); po[3] = f2b(y3);
}

// ------------------------------ launch -------------------------------------
extern "C" void kernel_launch(void* const* d_in, const int* in_sizes, int n_in,
                              void* d_out, int out_size, void* d_ws, size_t ws_size,
                              hipStream_t stream) {
  const float* state = (const float*)d_in[0];
  const float* conv_w = (const float*)d_in[1];
  const float* conv_b = (const float*)d_in[2];
  const float* qkv_w = (const float*)d_in[3];
  const float* qkv_b = (const float*)d_in[4];
  const float* o_w = (const float*)d_in[5];
  const float* o_b = (const float*)d_in[6];
  const float* attn_bias = (const float*)d_in[7];
  const float* ffp_w = (const float*)d_in[8];
  const float* ffp_b = (const float*)d_in[9];
  const float* ffg_w = (const float*)d_in[10];
  const float* ffg_b = (const float*)d_in[11];
  const float* ffo_w = (const float*)d_in[12];
  const float* ffo_b = (const float*)d_in[13];
  const float* n1_g = (const float*)d_in[14];
  const float* n1_b = (const float*)d_in[15];
  const float* n2_g = (const float*)d_in[16];
  const float* n2_b = (const float*)d_in[17];
  const float* n3_g = (const float*)d_in[18];
  const float* n3_b = (const float*)d_in[19];

  // ---- workspace layout: 137,527,296 bytes, phase-overlapped ----
  constexpr size_t kWsNeed = 137527296;
  if (ws_size < kWsNeed) {
    fprintf(stderr, "[kernel] ws_size=%zu < need=%zu\n", ws_size, kWsNeed);
    return;
  }
  char* ws = (char*)d_ws;
  u16* Wc = (u16*)(ws + 0);             // [27][256][256] bf16  (3,538,944 B)
  u16* Wqkv = (u16*)(ws + 3538944);     // [768][256]
  u16* Wo = (u16*)(ws + 3932160);       // [256][256]
  u16* Wff = (u16*)(ws + 4063232);      // [2048][256] (proj;gate)
  u16* Wffo = (u16*)(ws + 5111808);     // [256][1024]  (ends 5,636,096)
  float* stF = (float*)(ws + 5636096);  // [36800][256] f32 state (37,683,200 B)
  u16* stB = (u16*)(ws + 43319296);     // [36800][256] bf16 (18,841,600 B)
  char* S4 = ws + 62160896;             // 75,366,400 B shared slot
  // conv phase overlays:
  u16* X0 = (u16*)(ws + 5636096);       // in stF slot: [64][576][256] bf16
  u16* zrow = (u16*)(ws + 43319296);    // in stB slot: 256 zeros
  u16* pd = (u16*)S4;                   // 3 partials, stride kPdStride u16
  // attn/ffn phase overlays:
  u16* qkvb = (u16*)S4;                 // [36800][768] bf16 (56.5 MB)
  u16* attnout = (u16*)(S4 + 56524800); // [36800][256] bf16
  u16* oprojb = (u16*)S4;               // [36800][256] bf16
  u16* ffh = (u16*)S4;                  // [36800][1024] bf16 (75.4 MB)
  float* outp = (float*)d_out;

  // ---- pack weights / inputs to bf16 (every call; no cached state) ----
  k_pack_convw<<<768, 256, 0, stream>>>(conv_w, Wc);
  k_pack_wall<<<1024, 256, 0, stream>>>(qkv_w, o_w, ffp_w, ffg_w, ffo_w,
                                        Wqkv, Wo, Wff, Wffo);
  k_make_x0<<<kB * kP + 1, 256, 0, stream>>>(state, X0, zrow);

  // ---- conv (3 dilation partials) + LN1 ----
  k_conv<<<dim3(288, 2, 3), 256, 0, stream>>>(X0, zrow, Wc, conv_b, pd);
  k_add_ln3<<<kRows / 4, 256, 0, stream>>>(state, pd, pd + kPdStride, pd + 2 * kPdStride,
                                           n1_g, n1_b, stF, stB);

  // ---- attention ----
  k_gemm<<<dim3(288, 6), 256, 0, stream>>>(stB, Wqkv, qkv_b, qkvb, kRows, 768, 256);
  k_attn2<<<dim3(9, kH, kB), 256, 0, stream>>>(qkvb, attn_bias, attnout);
  k_gemm<<<dim3(288, 2), 256, 0, stream>>>(attnout, Wo, o_b, oprojb, kRows, 256, 256);
  k_add_ln<<<kRows / 4, 256, 0, stream>>>(stF, oprojb, n2_g, n2_b, stF, stB);

  // ---- FFN ----
  k_ff1<<<dim3(288, 8), 256, 0, stream>>>(stB, Wff, ffp_b, ffg_b, ffh, kRows);
  k_gemm<<<dim3(288, 2), 256, 0, stream>>>(ffh, Wffo, ffo_b, stB, kRows, 256, 1024);
  k_add_ln<<<kRows / 4, 256, 0, stream>>>(stF, stB, n3_g, n3_b, outp, nullptr);
}